// Round 3
// baseline (3398.699 us; speedup 1.0000x reference)
//
#include <hip/hip_runtime.h>

#define NENT 40000
#define NB 128
#define NQ 24
#define NOPS 12
#define EPO 300000
#define NTOT (NOPS * EPO)
#define NRANK 3
#define NPASS 8
#define CP 16   // batch columns per pass

typedef float v2f __attribute__((ext_vector_type(2)));
typedef int   v2i __attribute__((ext_vector_type(2)));

// ---------------- CSR build: 4-way split counters to cut same-address atomic serialization ----------------
__global__ void hist2_kernel(const int* __restrict__ src, const int* __restrict__ dst,
                             int* __restrict__ cnt4S, int* __restrict__ cnt4D) {
    int i = blockIdx.x * 256 + threadIdx.x;
    if (i < NTOT) {
        int sub = i & 3;
        atomicAdd(&cnt4S[src[i] * 4 + sub], 1);
        atomicAdd(&cnt4D[dst[i] * 4 + sub], 1);
    }
}

__global__ void scan2_kernel(const int* __restrict__ cnt4_all, int* __restrict__ rp_all,
                             int* __restrict__ rp4_all) {
    const int* cnt4 = cnt4_all + blockIdx.x * NENT * 4;
    int* rp  = rp_all  + blockIdx.x * (NENT + 1);
    int* rp4 = rp4_all + blockIdx.x * NENT * 4;
    __shared__ int part[1024];
    int t = threadIdx.x;
    int beg = t * 40;
    int end = min(NENT, beg + 40);
    int s = 0;
    for (int i = beg * 4; i < end * 4; ++i) s += cnt4[i];
    part[t] = s;
    __syncthreads();
    for (int offs = 1; offs < 1024; offs <<= 1) {
        int add = (t >= offs) ? part[t - offs] : 0;
        __syncthreads();
        part[t] += add;
        __syncthreads();
    }
    int run = part[t] - s;
    for (int key = beg; key < end; ++key) {
        rp[key] = run;
        for (int sub = 0; sub < 4; ++sub) {
            rp4[key * 4 + sub] = run;
            run += cnt4[key * 4 + sub];
        }
    }
    if (t == 1023) rp[NENT] = part[1023];
}

__global__ void scatter2_kernel(const int* __restrict__ src, const int* __restrict__ dst,
                                const float* __restrict__ val,
                                const int* __restrict__ rp4S, const int* __restrict__ rp4D,
                                int* __restrict__ fill4S, int* __restrict__ fill4D,
                                int2* __restrict__ eS, int2* __restrict__ eD) {
    int i = blockIdx.x * 256 + threadIdx.x;
    if (i >= NTOT) return;
    int sub = i & 3;
    int s = src[i], d = dst[i];
    int op = i / EPO;
    int v = __float_as_int(val[i]);
    int ps = atomicAdd(&fill4S[s * 4 + sub], 1);
    eS[rp4S[s * 4 + sub] + ps] = make_int2(d | (op << 16), v);
    int pd = atomicAdd(&fill4D[d * 4 + sub], 1);
    eD[rp4D[d * 4 + sub] + pd] = make_int2(s | (op << 16), v);
}

// ---------------- LSTM (deduped: only 24 distinct query columns) ----------------
__global__ void zxq_kernel(const float* __restrict__ emb,
                           const float* __restrict__ Wih_f, const float* __restrict__ bih_f,
                           const float* __restrict__ bhh_f,
                           const float* __restrict__ Wih_b, const float* __restrict__ bih_b,
                           const float* __restrict__ bhh_b,
                           float* __restrict__ zxq) {
    int combo = blockIdx.x / NQ;
    int q = blockIdx.x % NQ;
    int dir = combo / 3, r = combo % 3;
    const float* Wih = (dir ? Wih_b : Wih_f) + r * 512 * 128;
    const float* bih = (dir ? bih_b : bih_f) + r * 512;
    const float* bhh = (dir ? bhh_b : bhh_f) + r * 512;
    __shared__ float x[128];
    int u = threadIdx.x;
    x[u] = emb[q * 128 + u];
    __syncthreads();
    const float* W0p = Wih + u * 128;
    const float* W1p = Wih + (128 + u) * 128;
    const float* W2p = Wih + (256 + u) * 128;
    const float* W3p = Wih + (384 + u) * 128;
    float a0 = 0.f, a1 = 0.f, a2 = 0.f, a3 = 0.f;
    for (int d = 0; d < 128; ++d) {
        float xv = x[d];
        a0 = fmaf(xv, W0p[d], a0);
        a1 = fmaf(xv, W1p[d], a1);
        a2 = fmaf(xv, W2p[d], a2);
        a3 = fmaf(xv, W3p[d], a3);
    }
    float* o = zxq + (size_t)(combo * NQ + q) * 512;
    o[u]       = a0 + bih[u]       + bhh[u];
    o[128 + u] = a1 + bih[128 + u] + bhh[128 + u];
    o[256 + u] = a2 + bih[256 + u] + bhh[256 + u];
    o[384 + u] = a3 + bih[384 + u] + bhh[384 + u];
}

__global__ void lstmq_kernel(const float* __restrict__ Whh_f, const float* __restrict__ Whh_b,
                             const float* __restrict__ zxq, float* __restrict__ hq) {
    int combo = blockIdx.x / NQ;
    int q = blockIdx.x % NQ;
    int dir = combo / 3, r = combo % 3;
    const float* Whh = (dir ? Whh_b : Whh_f) + r * 512 * 128;
    __shared__ float h[128];
    int u = threadIdx.x;
    const float* z = zxq + (size_t)(combo * NQ + q) * 512;
    float zi0 = z[u], zf0 = z[128 + u], zg0 = z[256 + u], zo0 = z[384 + u];
    const float* Wi = Whh + u * 128;
    const float* Wf = Whh + (128 + u) * 128;
    const float* Wg = Whh + (256 + u) * 128;
    const float* Wo = Whh + (384 + u) * 128;
    float c = 0.f;
    h[u] = 0.f;
    for (int s = 0; s < 3; ++s) {
        __syncthreads();
        float a0 = 0.f, a1 = 0.f, a2 = 0.f, a3 = 0.f;
        for (int d = 0; d < 128; ++d) {
            float hv = h[d];
            a0 = fmaf(hv, Wi[d], a0);
            a1 = fmaf(hv, Wf[d], a1);
            a2 = fmaf(hv, Wg[d], a2);
            a3 = fmaf(hv, Wo[d], a3);
        }
        float ig = 1.f / (1.f + expf(-(zi0 + a0)));
        float fg = 1.f / (1.f + expf(-(zf0 + a1)));
        float gg = tanhf(zg0 + a2);
        float og = 1.f / (1.f + expf(-(zo0 + a3)));
        c = fg * c + ig * gg;
        float hn = og * tanhf(c);
        __syncthreads();
        h[u] = hn;
        hq[(size_t)((combo * 3 + s) * NQ + q) * 128 + u] = hn;
    }
}

__global__ void attnq_kernel(const float* __restrict__ hq, const float* __restrict__ W0,
                             const float* __restrict__ b0, float* __restrict__ attnq) {
    int r = blockIdx.x / 3, t = blockIdx.x % 3;
    __shared__ float W0s[256 * 13];
    for (int idx = threadIdx.x; idx < 256 * 13; idx += 32) W0s[idx] = W0[idx];
    __syncthreads();
    int q = threadIdx.x;
    if (q >= NQ) return;
    float acc[13];
    for (int k = 0; k < 13; ++k) acc[k] = b0[k];
    const float* hf = hq + (size_t)(((0 * 3 + r) * 3 + t) * NQ + q) * 128;
    const float* hb = hq + (size_t)(((1 * 3 + r) * 3 + (2 - t)) * NQ + q) * 128;
    for (int u = 0; u < 128; ++u) {
        float v = hf[u];
        for (int k = 0; k < 13; ++k) acc[k] = fmaf(v, W0s[u * 13 + k], acc[k]);
    }
    for (int u = 0; u < 128; ++u) {
        float v = hb[u];
        for (int k = 0; k < 13; ++k) acc[k] = fmaf(v, W0s[(128 + u) * 13 + k], acc[k]);
    }
    float m = acc[0];
    for (int k = 1; k < 13; ++k) m = fmaxf(m, acc[k]);
    float e[13];
    float sum = 0.f;
    for (int k = 0; k < 13; ++k) { e[k] = expf(acc[k] - m); sum += e[k]; }
    float inv = 1.f / sum;
    float* ao = attnq + (size_t)(r * 3 + t) * 13 * NQ;
    for (int k = 0; k < 13; ++k) ao[k * NQ + q] = e[k] * inv;
}

// attn[(rt*13+k)*128+b] = attnq[(rt*13+k)*24 + queries[b]]
__global__ void expand_kernel(const int* __restrict__ queries, const float* __restrict__ attnq,
                              float* __restrict__ attn) {
    __shared__ int qs[128];
    if (threadIdx.x < 128) qs[threadIdx.x] = queries[threadIdx.x];
    __syncthreads();
    for (int idx = threadIdx.x; idx < 9 * 13 * 128; idx += 256) {
        int b = idx & 127, kk = idx >> 7;
        attn[idx] = attnq[kk * NQ + qs[b]];
    }
}

// ---------------- steps 0+1, sparse expansion; writes pass-major mem[r][p][j][c] ----------------
__global__ void fused01_kernel(const int* __restrict__ heads, const float* __restrict__ attn,
                               const int* __restrict__ rpS, const int2* __restrict__ edgesS,
                               float* __restrict__ mem2) {
    int r = blockIdx.y;
    int b = blockIdx.x;
    __shared__ float c0s[13], c1s[13];
    if (threadIdx.x < 13) {
        c0s[threadIdx.x] = attn[(size_t)((r * 3 + 0) * 13 + threadIdx.x) * 128 + b];
        c1s[threadIdx.x] = attn[(size_t)((r * 3 + 1) * 13 + threadIdx.x) * 128 + b];
    }
    __syncthreads();
    int h = heads[b];
    int beg = rpS[h], end = rpS[h + 1];
    int nE = end - beg + 1;
    float* mem = mem2 + ((size_t)(r * NPASS + (b >> 4)) * NENT) * CP + (b & 15);
    for (int ent = threadIdx.x; ent < nE; ent += 128) {
        int i; float wv;
        if (ent == 0) { i = h; wv = c0s[12]; }
        else {
            int2 e = edgesS[beg + ent - 1];
            i = e.x & 0xFFFF;
            wv = __int_as_float(e.y) * c0s[e.x >> 16];
        }
        atomicAdd(&mem[(size_t)i * CP], c1s[12] * wv);
        int fb = rpS[i], fe = rpS[i + 1];
        for (int f = fb; f < fe; ++f) {
            int2 e2 = edgesS[f];
            atomicAdd(&mem[(size_t)(e2.x & 0xFFFF) * CP],
                      __int_as_float(e2.y) * c1s[e2.x >> 16] * wv);
        }
    }
}

// ---------------- step 2, dense gather; blockIdx.x = pass -> pinned to one XCD (id%8 round-robin) ----------------
__global__ __launch_bounds__(256) void dense_kernel(const float* __restrict__ attn,
                                                    const int* __restrict__ rpD,
                                                    const int2* __restrict__ edgesD,
                                                    const float* __restrict__ in,
                                                    float* __restrict__ out) {
    int p = blockIdx.x;   // pass = XCD
    int r = blockIdx.z;
    __shared__ float cs[13 * CP];
    if (threadIdx.x < 13 * CP) {
        int op = threadIdx.x / CP, c0 = threadIdx.x % CP;
        cs[threadIdx.x] = attn[(size_t)((r * 3 + 2) * 13 + op) * 128 + p * CP + c0];
    }
    __syncthreads();
    int lane = threadIdx.x & 63;
    int wave = threadIdx.x >> 6;
    int e = lane >> 4;       // 4 edge-slots
    int c = lane & 15;       // 16 cols
    const float* inr = in + (size_t)(r * NPASS + p) * NENT * CP;
    float* outr = out + (size_t)(r * NPASS + p) * NENT * CP;
    float cid = cs[12 * CP + c];
    int j0 = blockIdx.y * 32 + wave * 8;
    for (int rr = 0; rr < 8; ++rr) {
        int j = j0 + rr;
        int kb = rpD[j];
        int len = rpD[j + 1] - kb;
        float acc = 0.f;
        for (int i4 = e; i4 < len; i4 += 4) {
            v2i ed = __builtin_nontemporal_load((const v2i*)&edgesD[kb + i4]);
            int srcv = ed.x & 0xFFFF;
            float v = __int_as_float(ed.y);
            acc = fmaf(v * cs[(ed.x >> 16) * CP + c], inr[(size_t)srcv * CP + c], acc);
        }
        acc += __shfl_xor(acc, 16);
        acc += __shfl_xor(acc, 32);
        float res = fmaf(cid, inr[(size_t)j * CP + c], acc);
        if (e == 0) __builtin_nontemporal_store(res, &outr[(size_t)j * CP + c]);
    }
}

// ---------------- epilogue (pass-major reads) ----------------
__global__ void norm_kernel(const float* __restrict__ mem3, float* __restrict__ normv) {
    int p = blockIdx.y, r = blockIdx.z;
    int c = threadIdx.x & 15, jj = threadIdx.x >> 4;
    const float* m = mem3 + ((size_t)(r * NPASS + p) * NENT + (size_t)blockIdx.x * 320) * CP;
    float acc = 0.f;
    for (int j = jj; j < 320; j += 16) acc += m[(size_t)j * CP + c];
    __shared__ float red[256];
    red[threadIdx.x] = acc;
    __syncthreads();
    for (int s = 128; s >= 16; s >>= 1) {
        if (threadIdx.x < s) red[threadIdx.x] += red[threadIdx.x + s];
        __syncthreads();
    }
    if (threadIdx.x < 16) atomicAdd(&normv[r * 128 + p * CP + threadIdx.x], red[threadIdx.x]);
}

__global__ void rnorm_kernel(const float* __restrict__ normv, float* __restrict__ rnormv) {
    int i = threadIdx.x;
    rnormv[i] = 1.f / fmaxf(normv[i], 1e-20f);
}

__global__ void final_kernel(const float* __restrict__ mem3, const float* __restrict__ rnormv,
                             float* __restrict__ out) {
    __shared__ float tile[32 * 129];
    __shared__ float rn[384];
    for (int idx = threadIdx.x; idx < 384; idx += 256) rn[idx] = rnormv[idx];
    __syncthreads();
    int j0 = blockIdx.x * 32;
    for (int p = 0; p < NPASS; ++p) {
        for (int it = 0; it < 2; ++it) {
            int lin = it * 256 + threadIdx.x;
            int jj = lin >> 4, c = lin & 15;
            int b = p * CP + c;
            float s = 0.f;
            for (int r = 0; r < 3; ++r)
                s += mem3[((size_t)(r * NPASS + p) * NENT + j0 + jj) * CP + c] * rn[r * 128 + b];
            tile[jj * 129 + b] = s;
        }
    }
    __syncthreads();
    for (int it = 0; it < 16; ++it) {
        int lin = it * 256 + threadIdx.x;
        int b = lin >> 5, jj = lin & 31;
        out[(size_t)b * NENT + j0 + jj] = tile[jj * 129 + b];
    }
}

extern "C" void kernel_launch(void* const* d_in, const int* in_sizes, int n_in,
                              void* d_out, int out_size, void* d_ws, size_t ws_size,
                              hipStream_t stream) {
    const int*   queries  = (const int*)d_in[0];
    const int*   heads    = (const int*)d_in[1];
    const int*   edge_src = (const int*)d_in[2];
    const int*   edge_dst = (const int*)d_in[3];
    const float* edge_val = (const float*)d_in[4];
    const float* emb      = (const float*)d_in[5];
    const float* Wih_f    = (const float*)d_in[6];
    const float* Whh_f    = (const float*)d_in[7];
    const float* bih_f    = (const float*)d_in[8];
    const float* bhh_f    = (const float*)d_in[9];
    const float* Wih_b    = (const float*)d_in[10];
    const float* Whh_b    = (const float*)d_in[11];
    const float* bih_b    = (const float*)d_in[12];
    const float* bhh_b    = (const float*)d_in[13];
    const float* W0       = (const float*)d_in[14];
    const float* b0       = (const float*)d_in[15];
    float* out = (float*)d_out;

    char* w = (char*)d_ws;
    size_t off = 0;
    auto alloc = [&](size_t bytes) -> void* {
        off = (off + 255) & ~(size_t)255;
        void* p = w + off;
        off += bytes;
        return p;
    };
    float* attnq  = (float*)alloc((size_t)9 * 13 * NQ * sizeof(float));
    float* attn   = (float*)alloc((size_t)9 * 13 * 128 * sizeof(float));
    float* zxq    = (float*)alloc((size_t)6 * NQ * 512 * sizeof(float));
    float* hq     = (float*)alloc((size_t)6 * 3 * NQ * 128 * sizeof(float));
    int*   rp2    = (int*)alloc((size_t)2 * (NENT + 1) * sizeof(int));
    int*   rp4    = (int*)alloc((size_t)2 * NENT * 4 * sizeof(int));
    int*   cnt4   = (int*)alloc((size_t)2 * NENT * 4 * sizeof(int));
    int2*  edgesS = (int2*)alloc((size_t)NTOT * sizeof(int2));
    int2*  edgesD = (int2*)alloc((size_t)NTOT * sizeof(int2));
    float* mem2   = (float*)alloc((size_t)NRANK * NENT * NB * sizeof(float));
    float* mem3   = (float*)alloc((size_t)NRANK * NENT * NB * sizeof(float));
    float* normv  = (float*)alloc((size_t)NRANK * NB * sizeof(float));
    float* rnormv = (float*)alloc((size_t)NRANK * NB * sizeof(float));

    int* rpS = rp2;
    int* rpD = rp2 + (NENT + 1);
    int* rp4S = rp4;
    int* rp4D = rp4 + NENT * 4;
    int* cnt4S = cnt4;
    int* cnt4D = cnt4 + NENT * 4;

    int histGrid = (NTOT + 255) / 256;

    // CSR build
    hipMemsetAsync(cnt4, 0, 2 * NENT * 4 * sizeof(int), stream);
    hist2_kernel<<<histGrid, 256, 0, stream>>>(edge_src, edge_dst, cnt4S, cnt4D);
    scan2_kernel<<<2, 1024, 0, stream>>>(cnt4, rp2, rp4);
    hipMemsetAsync(cnt4, 0, 2 * NENT * 4 * sizeof(int), stream);
    scatter2_kernel<<<histGrid, 256, 0, stream>>>(edge_src, edge_dst, edge_val,
                                                  rp4S, rp4D, cnt4S, cnt4D, edgesS, edgesD);

    // LSTM + attention (deduped over 24 queries)
    zxq_kernel<<<6 * NQ, 128, 0, stream>>>(emb, Wih_f, bih_f, bhh_f, Wih_b, bih_b, bhh_b, zxq);
    lstmq_kernel<<<6 * NQ, 128, 0, stream>>>(Whh_f, Whh_b, zxq, hq);
    attnq_kernel<<<9, 32, 0, stream>>>(hq, W0, b0, attnq);
    expand_kernel<<<1, 256, 0, stream>>>(queries, attnq, attn);

    // steps 0+1 sparse, step 2 dense
    hipMemsetAsync(mem2, 0, (size_t)NRANK * NENT * NB * sizeof(float), stream);
    {
        dim3 g(NB, NRANK);
        fused01_kernel<<<g, 128, 0, stream>>>(heads, attn, rpS, edgesS, mem2);
    }
    {
        dim3 g(NPASS, NENT / 32, NRANK);
        dense_kernel<<<g, 256, 0, stream>>>(attn, rpD, edgesD, mem2, mem3);
    }

    // epilogue
    hipMemsetAsync(normv, 0, NRANK * NB * sizeof(float), stream);
    {
        dim3 g(NENT / 320, NPASS, NRANK);
        norm_kernel<<<g, 256, 0, stream>>>(mem3, normv);
    }
    rnorm_kernel<<<1, NRANK * NB, 0, stream>>>(normv, rnormv);
    final_kernel<<<NENT / 32, 256, 0, stream>>>(mem3, rnormv, out);
}

// Round 4
// 2527.195 us; speedup vs baseline: 1.3449x; 1.3449x over previous
//
#include <hip/hip_runtime.h>

#define NENT 40000
#define NB 128
#define NQ 24
#define NOPS 12
#define EPO 300000
#define NTOT (NOPS * EPO)
#define NRANK 3
#define NPASS 8
#define CP 16     // batch columns per pass
#define CHUNK 1024  // edges per staged LDS chunk

typedef float v2f __attribute__((ext_vector_type(2)));
typedef int   v2i __attribute__((ext_vector_type(2)));

// async global->LDS, 16B per lane; LDS dest = wave-uniform base + lane*16
__device__ __forceinline__ void gld16(const int2* g, int2* l) {
    typedef __attribute__((address_space(1))) const unsigned char ga_t;
    typedef __attribute__((address_space(3))) unsigned char la_t;
    __builtin_amdgcn_global_load_lds((const ga_t*)g, (la_t*)l, 16, 0, 0);
}

// ---------------- CSR build: 4-way split counters ----------------
__global__ void hist2_kernel(const int* __restrict__ src, const int* __restrict__ dst,
                             int* __restrict__ cnt4S, int* __restrict__ cnt4D) {
    int i = blockIdx.x * 256 + threadIdx.x;
    if (i < NTOT) {
        int sub = i & 3;
        atomicAdd(&cnt4S[src[i] * 4 + sub], 1);
        atomicAdd(&cnt4D[dst[i] * 4 + sub], 1);
    }
}

__global__ void scan2_kernel(const int* __restrict__ cnt4_all, int* __restrict__ rp_all,
                             int* __restrict__ rp4_all) {
    const int* cnt4 = cnt4_all + blockIdx.x * NENT * 4;
    int* rp  = rp_all  + blockIdx.x * (NENT + 1);
    int* rp4 = rp4_all + blockIdx.x * NENT * 4;
    __shared__ int part[1024];
    int t = threadIdx.x;
    int beg = t * 40;
    int end = min(NENT, beg + 40);
    int s = 0;
    for (int i = beg * 4; i < end * 4; ++i) s += cnt4[i];
    part[t] = s;
    __syncthreads();
    for (int offs = 1; offs < 1024; offs <<= 1) {
        int add = (t >= offs) ? part[t - offs] : 0;
        __syncthreads();
        part[t] += add;
        __syncthreads();
    }
    int run = part[t] - s;
    for (int key = beg; key < end; ++key) {
        rp[key] = run;
        for (int sub = 0; sub < 4; ++sub) {
            rp4[key * 4 + sub] = run;
            run += cnt4[key * 4 + sub];
        }
    }
    if (t == 1023) rp[NENT] = part[1023];
}

__global__ void scatter2_kernel(const int* __restrict__ src, const int* __restrict__ dst,
                                const float* __restrict__ val,
                                const int* __restrict__ rp4S, const int* __restrict__ rp4D,
                                int* __restrict__ fill4S, int* __restrict__ fill4D,
                                int2* __restrict__ eS, int2* __restrict__ eD) {
    int i = blockIdx.x * 256 + threadIdx.x;
    if (i >= NTOT) return;
    int sub = i & 3;
    int s = src[i], d = dst[i];
    int op = i / EPO;
    int v = __float_as_int(val[i]);
    int ps = atomicAdd(&fill4S[s * 4 + sub], 1);
    eS[rp4S[s * 4 + sub] + ps] = make_int2(d | (op << 16), v);
    int pd = atomicAdd(&fill4D[d * 4 + sub], 1);
    eD[rp4D[d * 4 + sub] + pd] = make_int2(s | (op << 16), v);
}

// ---------------- LSTM (deduped over 24 distinct query values) ----------------
__global__ void zxq_kernel(const float* __restrict__ emb,
                           const float* __restrict__ Wih_f, const float* __restrict__ bih_f,
                           const float* __restrict__ bhh_f,
                           const float* __restrict__ Wih_b, const float* __restrict__ bih_b,
                           const float* __restrict__ bhh_b,
                           float* __restrict__ zxq) {
    int combo = blockIdx.x / NQ;
    int q = blockIdx.x % NQ;
    int dir = combo / 3, r = combo % 3;
    const float* Wih = (dir ? Wih_b : Wih_f) + r * 512 * 128;
    const float* bih = (dir ? bih_b : bih_f) + r * 512;
    const float* bhh = (dir ? bhh_b : bhh_f) + r * 512;
    __shared__ float x[128];
    int u = threadIdx.x;
    x[u] = emb[q * 128 + u];
    __syncthreads();
    const float* W0p = Wih + u * 128;
    const float* W1p = Wih + (128 + u) * 128;
    const float* W2p = Wih + (256 + u) * 128;
    const float* W3p = Wih + (384 + u) * 128;
    float a0 = 0.f, a1 = 0.f, a2 = 0.f, a3 = 0.f;
    for (int d = 0; d < 128; ++d) {
        float xv = x[d];
        a0 = fmaf(xv, W0p[d], a0);
        a1 = fmaf(xv, W1p[d], a1);
        a2 = fmaf(xv, W2p[d], a2);
        a3 = fmaf(xv, W3p[d], a3);
    }
    float* o = zxq + (size_t)(combo * NQ + q) * 512;
    o[u]       = a0 + bih[u]       + bhh[u];
    o[128 + u] = a1 + bih[128 + u] + bhh[128 + u];
    o[256 + u] = a2 + bih[256 + u] + bhh[256 + u];
    o[384 + u] = a3 + bih[384 + u] + bhh[384 + u];
}

__global__ void lstmq_kernel(const float* __restrict__ Whh_f, const float* __restrict__ Whh_b,
                             const float* __restrict__ zxq, float* __restrict__ hq) {
    int combo = blockIdx.x / NQ;
    int q = blockIdx.x % NQ;
    int dir = combo / 3, r = combo % 3;
    const float* Whh = (dir ? Whh_b : Whh_f) + r * 512 * 128;
    __shared__ float h[128];
    int u = threadIdx.x;
    const float* z = zxq + (size_t)(combo * NQ + q) * 512;
    float zi0 = z[u], zf0 = z[128 + u], zg0 = z[256 + u], zo0 = z[384 + u];
    const float* Wi = Whh + u * 128;
    const float* Wf = Whh + (128 + u) * 128;
    const float* Wg = Whh + (256 + u) * 128;
    const float* Wo = Whh + (384 + u) * 128;
    float c = 0.f;
    h[u] = 0.f;
    for (int s = 0; s < 3; ++s) {
        __syncthreads();
        float a0 = 0.f, a1 = 0.f, a2 = 0.f, a3 = 0.f;
        for (int d = 0; d < 128; ++d) {
            float hv = h[d];
            a0 = fmaf(hv, Wi[d], a0);
            a1 = fmaf(hv, Wf[d], a1);
            a2 = fmaf(hv, Wg[d], a2);
            a3 = fmaf(hv, Wo[d], a3);
        }
        float ig = 1.f / (1.f + expf(-(zi0 + a0)));
        float fg = 1.f / (1.f + expf(-(zf0 + a1)));
        float gg = tanhf(zg0 + a2);
        float og = 1.f / (1.f + expf(-(zo0 + a3)));
        c = fg * c + ig * gg;
        float hn = og * tanhf(c);
        __syncthreads();
        h[u] = hn;
        hq[(size_t)((combo * 3 + s) * NQ + q) * 128 + u] = hn;
    }
}

__global__ void attnq_kernel(const float* __restrict__ hq, const float* __restrict__ W0,
                             const float* __restrict__ b0, float* __restrict__ attnq) {
    int r = blockIdx.x / 3, t = blockIdx.x % 3;
    __shared__ float W0s[256 * 13];
    for (int idx = threadIdx.x; idx < 256 * 13; idx += 32) W0s[idx] = W0[idx];
    __syncthreads();
    int q = threadIdx.x;
    if (q >= NQ) return;
    float acc[13];
    for (int k = 0; k < 13; ++k) acc[k] = b0[k];
    const float* hf = hq + (size_t)(((0 * 3 + r) * 3 + t) * NQ + q) * 128;
    const float* hb = hq + (size_t)(((1 * 3 + r) * 3 + (2 - t)) * NQ + q) * 128;
    for (int u = 0; u < 128; ++u) {
        float v = hf[u];
        for (int k = 0; k < 13; ++k) acc[k] = fmaf(v, W0s[u * 13 + k], acc[k]);
    }
    for (int u = 0; u < 128; ++u) {
        float v = hb[u];
        for (int k = 0; k < 13; ++k) acc[k] = fmaf(v, W0s[(128 + u) * 13 + k], acc[k]);
    }
    float m = acc[0];
    for (int k = 1; k < 13; ++k) m = fmaxf(m, acc[k]);
    float e[13];
    float sum = 0.f;
    for (int k = 0; k < 13; ++k) { e[k] = expf(acc[k] - m); sum += e[k]; }
    float inv = 1.f / sum;
    float* ao = attnq + (size_t)(r * 3 + t) * 13 * NQ;
    for (int k = 0; k < 13; ++k) ao[k * NQ + q] = e[k] * inv;
}

__global__ void expand_kernel(const int* __restrict__ queries, const float* __restrict__ attnq,
                              float* __restrict__ attn) {
    __shared__ int qs[128];
    if (threadIdx.x < 128) qs[threadIdx.x] = queries[threadIdx.x];
    __syncthreads();
    for (int idx = threadIdx.x; idx < 9 * 13 * 128; idx += 256) {
        int b = idx & 127, kk = idx >> 7;
        attn[idx] = attnq[kk * NQ + qs[b]];
    }
}

// ---------------- steps 0+1, sparse expansion; writes pass-major mem[r][p][j][c] ----------------
__global__ void fused01_kernel(const int* __restrict__ heads, const float* __restrict__ attn,
                               const int* __restrict__ rpS, const int2* __restrict__ edgesS,
                               float* __restrict__ mem2) {
    int r = blockIdx.y;
    int b = blockIdx.x;
    __shared__ float c0s[13], c1s[13];
    if (threadIdx.x < 13) {
        c0s[threadIdx.x] = attn[(size_t)((r * 3 + 0) * 13 + threadIdx.x) * 128 + b];
        c1s[threadIdx.x] = attn[(size_t)((r * 3 + 1) * 13 + threadIdx.x) * 128 + b];
    }
    __syncthreads();
    int h = heads[b];
    int beg = rpS[h], end = rpS[h + 1];
    int nE = end - beg + 1;
    float* mem = mem2 + ((size_t)(r * NPASS + (b >> 4)) * NENT) * CP + (b & 15);
    for (int ent = threadIdx.x; ent < nE; ent += 128) {
        int i; float wv;
        if (ent == 0) { i = h; wv = c0s[12]; }
        else {
            int2 e = edgesS[beg + ent - 1];
            i = e.x & 0xFFFF;
            wv = __int_as_float(e.y) * c0s[e.x >> 16];
        }
        atomicAdd(&mem[(size_t)i * CP], c1s[12] * wv);
        int fb = rpS[i], fe = rpS[i + 1];
        for (int f = fb; f < fe; ++f) {
            int2 e2 = edgesS[f];
            atomicAdd(&mem[(size_t)(e2.x & 0xFFFF) * CP],
                      __int_as_float(e2.y) * c1s[e2.x >> 16] * wv);
        }
    }
}

// ---------------- step 2, dense gather; blockIdx.x = pass -> pinned XCD; LDS-staged edges ----------------
__global__ __launch_bounds__(256) void dense_kernel(const float* __restrict__ attn,
                                                    const int* __restrict__ rpD,
                                                    const int2* __restrict__ edgesD,
                                                    const float* __restrict__ in,
                                                    float* __restrict__ out,
                                                    float* __restrict__ normv) {
    int p = blockIdx.x;   // pass = XCD (linear-id % 8 round-robin)
    int r = blockIdx.z;
    __shared__ int2 ebuf[2][CHUNK];
    __shared__ float cs[13 * 17];     // stride 17: kill bank conflicts
    __shared__ float npart[4][16];
    int tid = threadIdx.x;
    if (tid < 13 * 16) {
        int op = tid >> 4, c0 = tid & 15;
        cs[op * 17 + c0] = attn[(size_t)((r * 3 + 2) * 13 + op) * 128 + p * CP + c0];
    }
    int wave = tid >> 6, lane = tid & 63;
    int e = lane >> 4, c = lane & 15;
    int j0 = blockIdx.y * 32;
    const float* inr = in + (size_t)(r * NPASS + p) * NENT * CP;
    float* outr = out + (size_t)(r * NPASS + p) * NENT * CP;
    int jw = j0 + wave * 8;
    int rb[9];
#pragma unroll
    for (int i = 0; i < 9; ++i) rb[i] = rpD[jw + i];
    int ebase = rpD[j0] & ~1;      // 16B-aligned chunk origin
    int kend = rpD[j0 + 32];
    int nch = (kend - ebase + CHUNK - 1) / CHUNK;

    auto stage = [&](int buf, int bb) {
        int ia = bb + tid * 2;       if (ia > NTOT - 2) ia = NTOT - 2;
        int ib = bb + 512 + tid * 2; if (ib > NTOT - 2) ib = NTOT - 2;
        gld16(&edgesD[ia], &ebuf[buf][wave * 128]);
        gld16(&edgesD[ib], &ebuf[buf][512 + wave * 128]);
    };

    stage(0, ebase);
    float acc[8] = {0.f, 0.f, 0.f, 0.f, 0.f, 0.f, 0.f, 0.f};
    for (int ch = 0; ch < nch; ++ch) {
        __syncthreads();   // drains vmcnt: buf[ch&1] staged; prior reads of other buf done
        if (ch + 1 < nch) stage((ch + 1) & 1, ebase + (ch + 1) * CHUNK);
        int cb = ebase + ch * CHUNK;
        int ce = min(cb + CHUNK, kend);
        const int2* lb = ebuf[ch & 1];
#pragma unroll
        for (int rr = 0; rr < 8; ++rr) {
            int lo = max(rb[rr], cb) + e;
            int hi = min(rb[rr + 1], ce);
            float a = acc[rr];
            for (int i = lo; i < hi; i += 4) {
                int2 ed = lb[i - cb];
                a = fmaf(__int_as_float(ed.y) * cs[(ed.x >> 16) * 17 + c],
                         inr[(size_t)(ed.x & 0xFFFF) * CP + c], a);
            }
            acc[rr] = a;
        }
    }
    float rsum = 0.f;
#pragma unroll
    for (int rr = 0; rr < 8; ++rr) {
        float red = acc[rr];
        red += __shfl_xor(red, 16);
        red += __shfl_xor(red, 32);
        if (e == 0) {
            int j = jw + rr;
            float res = fmaf(cs[12 * 17 + c], inr[(size_t)j * CP + c], red);
            __builtin_nontemporal_store(res, &outr[(size_t)j * CP + c]);
            rsum += res;
        }
    }
    if (e == 0) npart[wave][c] = rsum;
    __syncthreads();
    if (tid < 16) {
        float s = npart[0][tid] + npart[1][tid] + npart[2][tid] + npart[3][tid];
        atomicAdd(&normv[r * 128 + p * CP + tid], s);
    }
}

// ---------------- epilogue ----------------
__global__ void rnorm_kernel(const float* __restrict__ normv, float* __restrict__ rnormv) {
    int i = threadIdx.x;
    rnormv[i] = 1.f / fmaxf(normv[i], 1e-20f);
}

__global__ void final_kernel(const float* __restrict__ mem3, const float* __restrict__ rnormv,
                             float* __restrict__ out) {
    __shared__ float tile[32 * 129];
    __shared__ float rn[384];
    for (int idx = threadIdx.x; idx < 384; idx += 256) rn[idx] = rnormv[idx];
    __syncthreads();
    int j0 = blockIdx.x * 32;
    for (int p = 0; p < NPASS; ++p) {
        for (int it = 0; it < 2; ++it) {
            int lin = it * 256 + threadIdx.x;
            int jj = lin >> 4, c = lin & 15;
            int b = p * CP + c;
            float s = 0.f;
            for (int r = 0; r < 3; ++r)
                s += mem3[((size_t)(r * NPASS + p) * NENT + j0 + jj) * CP + c] * rn[r * 128 + b];
            tile[jj * 129 + b] = s;
        }
    }
    __syncthreads();
    for (int it = 0; it < 16; ++it) {
        int lin = it * 256 + threadIdx.x;
        int b = lin >> 5, jj = lin & 31;
        out[(size_t)b * NENT + j0 + jj] = tile[jj * 129 + b];
    }
}

extern "C" void kernel_launch(void* const* d_in, const int* in_sizes, int n_in,
                              void* d_out, int out_size, void* d_ws, size_t ws_size,
                              hipStream_t stream) {
    const int*   queries  = (const int*)d_in[0];
    const int*   heads    = (const int*)d_in[1];
    const int*   edge_src = (const int*)d_in[2];
    const int*   edge_dst = (const int*)d_in[3];
    const float* edge_val = (const float*)d_in[4];
    const float* emb      = (const float*)d_in[5];
    const float* Wih_f    = (const float*)d_in[6];
    const float* Whh_f    = (const float*)d_in[7];
    const float* bih_f    = (const float*)d_in[8];
    const float* bhh_f    = (const float*)d_in[9];
    const float* Wih_b    = (const float*)d_in[10];
    const float* Whh_b    = (const float*)d_in[11];
    const float* bih_b    = (const float*)d_in[12];
    const float* bhh_b    = (const float*)d_in[13];
    const float* W0       = (const float*)d_in[14];
    const float* b0       = (const float*)d_in[15];
    float* out = (float*)d_out;

    char* w = (char*)d_ws;
    size_t off = 0;
    auto alloc = [&](size_t bytes) -> void* {
        off = (off + 255) & ~(size_t)255;
        void* p = w + off;
        off += bytes;
        return p;
    };
    float* attnq  = (float*)alloc((size_t)9 * 13 * NQ * sizeof(float));
    float* attn   = (float*)alloc((size_t)9 * 13 * 128 * sizeof(float));
    float* zxq    = (float*)alloc((size_t)6 * NQ * 512 * sizeof(float));
    float* hq     = (float*)alloc((size_t)6 * 3 * NQ * 128 * sizeof(float));
    int*   rp2    = (int*)alloc((size_t)2 * (NENT + 1) * sizeof(int));
    int*   rp4    = (int*)alloc((size_t)2 * NENT * 4 * sizeof(int));
    int*   cnt4   = (int*)alloc((size_t)2 * NENT * 4 * sizeof(int));
    int2*  edgesS = (int2*)alloc((size_t)NTOT * sizeof(int2));
    int2*  edgesD = (int2*)alloc((size_t)NTOT * sizeof(int2));
    float* mem2   = (float*)alloc((size_t)NRANK * NENT * NB * sizeof(float));
    float* mem3   = (float*)alloc((size_t)NRANK * NENT * NB * sizeof(float));
    float* normv  = (float*)alloc((size_t)NRANK * NB * sizeof(float));
    float* rnormv = (float*)alloc((size_t)NRANK * NB * sizeof(float));

    int* rpS = rp2;
    int* rpD = rp2 + (NENT + 1);
    int* rp4S = rp4;
    int* rp4D = rp4 + NENT * 4;
    int* cnt4S = cnt4;
    int* cnt4D = cnt4 + NENT * 4;

    int histGrid = (NTOT + 255) / 256;

    // CSR build
    hipMemsetAsync(cnt4, 0, 2 * NENT * 4 * sizeof(int), stream);
    hist2_kernel<<<histGrid, 256, 0, stream>>>(edge_src, edge_dst, cnt4S, cnt4D);
    scan2_kernel<<<2, 1024, 0, stream>>>(cnt4, rp2, rp4);
    hipMemsetAsync(cnt4, 0, 2 * NENT * 4 * sizeof(int), stream);
    scatter2_kernel<<<histGrid, 256, 0, stream>>>(edge_src, edge_dst, edge_val,
                                                  rp4S, rp4D, cnt4S, cnt4D, edgesS, edgesD);

    // LSTM + attention (deduped over 24 queries)
    zxq_kernel<<<6 * NQ, 128, 0, stream>>>(emb, Wih_f, bih_f, bhh_f, Wih_b, bih_b, bhh_b, zxq);
    lstmq_kernel<<<6 * NQ, 128, 0, stream>>>(Whh_f, Whh_b, zxq, hq);
    attnq_kernel<<<9, 32, 0, stream>>>(hq, W0, b0, attnq);
    expand_kernel<<<1, 256, 0, stream>>>(queries, attnq, attn);

    // steps 0+1 sparse, step 2 dense (norm fused into dense)
    hipMemsetAsync(mem2, 0, (size_t)NRANK * NENT * NB * sizeof(float), stream);
    hipMemsetAsync(normv, 0, NRANK * NB * sizeof(float), stream);
    {
        dim3 g(NB, NRANK);
        fused01_kernel<<<g, 128, 0, stream>>>(heads, attn, rpS, edgesS, mem2);
    }
    {
        dim3 g(NPASS, NENT / 32, NRANK);
        dense_kernel<<<g, 256, 0, stream>>>(attn, rpD, edgesD, mem2, mem3, normv);
    }

    // epilogue
    rnorm_kernel<<<1, NRANK * NB, 0, stream>>>(normv, rnormv);
    final_kernel<<<NENT / 32, 256, 0, stream>>>(mem3, rnormv, out);
}

// Round 5
// 1629.438 us; speedup vs baseline: 2.0858x; 1.5510x over previous
//
#include <hip/hip_runtime.h>

#define NENT 40000
#define NB 128
#define NQ 24
#define NOPS 12
#define EPO 300000
#define NTOT (NOPS * EPO)
#define NRANK 3
#define NPASS 8
#define CP 16       // batch columns per pass
#define CHUNK 1024  // edges per staged LDS chunk

typedef float v4f __attribute__((ext_vector_type(4)));

// async global->LDS, 16B per lane; LDS dest = wave-uniform base + lane*16
__device__ __forceinline__ void gld16(const int2* g, int2* l) {
    typedef __attribute__((address_space(1))) const unsigned char ga_t;
    typedef __attribute__((address_space(3))) unsigned char la_t;
    __builtin_amdgcn_global_load_lds((const ga_t*)g, (la_t*)l, 16, 0, 0);
}

__device__ __forceinline__ v4f shfl_xor4(v4f x, int m) {
    v4f r;
    r.x = __shfl_xor(x.x, m);
    r.y = __shfl_xor(x.y, m);
    r.z = __shfl_xor(x.z, m);
    r.w = __shfl_xor(x.w, m);
    return r;
}

__device__ __forceinline__ bool bittest(const unsigned* bm, int i) {
    return (bm[i >> 5] >> (i & 31)) & 1u;
}

// ---------------- bitmaps: heads and heads ∪ N_out(heads) ----------------
__global__ void headmark_kernel(const int* __restrict__ heads, unsigned* __restrict__ bmH,
                                unsigned* __restrict__ bm2) {
    int h = heads[threadIdx.x];
    atomicOr(&bmH[h >> 5], 1u << (h & 31));
    atomicOr(&bm2[h >> 5], 1u << (h & 31));
}

__global__ void mark2_kernel(const int* __restrict__ src, const int* __restrict__ dst,
                             const unsigned* __restrict__ bmH, unsigned* __restrict__ bm2) {
    int i = blockIdx.x * 256 + threadIdx.x;
    if (i < NTOT) {
        int s = src[i];
        if (bittest(bmH, s)) {
            int d = dst[i];
            atomicOr(&bm2[d >> 5], 1u << (d & 31));
        }
    }
}

// ---------------- CSR build: dst always; src only for marked rows ----------------
__global__ void hist2_kernel(const int* __restrict__ src, const int* __restrict__ dst,
                             const unsigned* __restrict__ bm2,
                             int* __restrict__ cnt4S, int* __restrict__ cnt4D) {
    int i = blockIdx.x * 256 + threadIdx.x;
    if (i < NTOT) {
        int sub = i & 3;
        atomicAdd(&cnt4D[dst[i] * 4 + sub], 1);
        int s = src[i];
        if (bittest(bm2, s)) atomicAdd(&cnt4S[s * 4 + sub], 1);
    }
}

__global__ void scan2_kernel(const int* __restrict__ cnt4_all, int* __restrict__ rp_all,
                             int* __restrict__ rp4_all) {
    const int* cnt4 = cnt4_all + blockIdx.x * NENT * 4;
    int* rp  = rp_all  + blockIdx.x * (NENT + 1);
    int* rp4 = rp4_all + blockIdx.x * NENT * 4;
    __shared__ int part[1024];
    int t = threadIdx.x;
    int beg = t * 40;
    int end = min(NENT, beg + 40);
    int s = 0;
    for (int i = beg * 4; i < end * 4; ++i) s += cnt4[i];
    part[t] = s;
    __syncthreads();
    for (int offs = 1; offs < 1024; offs <<= 1) {
        int add = (t >= offs) ? part[t - offs] : 0;
        __syncthreads();
        part[t] += add;
        __syncthreads();
    }
    int run = part[t] - s;
    for (int key = beg; key < end; ++key) {
        rp[key] = run;
        for (int sub = 0; sub < 4; ++sub) {
            rp4[key * 4 + sub] = run;
            run += cnt4[key * 4 + sub];
        }
    }
    if (t == 1023) rp[NENT] = part[1023];
}

__global__ void scatter2_kernel(const int* __restrict__ src, const int* __restrict__ dst,
                                const float* __restrict__ val, const unsigned* __restrict__ bm2,
                                const int* __restrict__ rp4S, const int* __restrict__ rp4D,
                                int* __restrict__ fill4S, int* __restrict__ fill4D,
                                int2* __restrict__ eS, int2* __restrict__ eD) {
    int i = blockIdx.x * 256 + threadIdx.x;
    if (i >= NTOT) return;
    int sub = i & 3;
    int s = src[i], d = dst[i];
    int op = i / EPO;
    int v = __float_as_int(val[i]);
    int pd = atomicAdd(&fill4D[d * 4 + sub], 1);
    eD[rp4D[d * 4 + sub] + pd] = make_int2(s | (op << 16), v);
    if (bittest(bm2, s)) {
        int ps = atomicAdd(&fill4S[s * 4 + sub], 1);
        eS[rp4S[s * 4 + sub] + ps] = make_int2(d | (op << 16), v);
    }
}

// ---------------- LSTM (deduped over 24 distinct query values) ----------------
__global__ void zxq_kernel(const float* __restrict__ emb,
                           const float* __restrict__ Wih_f, const float* __restrict__ bih_f,
                           const float* __restrict__ bhh_f,
                           const float* __restrict__ Wih_b, const float* __restrict__ bih_b,
                           const float* __restrict__ bhh_b,
                           float* __restrict__ zxq) {
    int combo = blockIdx.x / NQ;
    int q = blockIdx.x % NQ;
    int dir = combo / 3, r = combo % 3;
    const float* Wih = (dir ? Wih_b : Wih_f) + r * 512 * 128;
    const float* bih = (dir ? bih_b : bih_f) + r * 512;
    const float* bhh = (dir ? bhh_b : bhh_f) + r * 512;
    __shared__ float x[128];
    int u = threadIdx.x;
    x[u] = emb[q * 128 + u];
    __syncthreads();
    const float* W0p = Wih + u * 128;
    const float* W1p = Wih + (128 + u) * 128;
    const float* W2p = Wih + (256 + u) * 128;
    const float* W3p = Wih + (384 + u) * 128;
    float a0 = 0.f, a1 = 0.f, a2 = 0.f, a3 = 0.f;
    for (int d = 0; d < 128; ++d) {
        float xv = x[d];
        a0 = fmaf(xv, W0p[d], a0);
        a1 = fmaf(xv, W1p[d], a1);
        a2 = fmaf(xv, W2p[d], a2);
        a3 = fmaf(xv, W3p[d], a3);
    }
    float* o = zxq + (size_t)(combo * NQ + q) * 512;
    o[u]       = a0 + bih[u]       + bhh[u];
    o[128 + u] = a1 + bih[128 + u] + bhh[128 + u];
    o[256 + u] = a2 + bih[256 + u] + bhh[256 + u];
    o[384 + u] = a3 + bih[384 + u] + bhh[384 + u];
}

__global__ void lstmq_kernel(const float* __restrict__ Whh_f, const float* __restrict__ Whh_b,
                             const float* __restrict__ zxq, float* __restrict__ hq) {
    int combo = blockIdx.x / NQ;
    int q = blockIdx.x % NQ;
    int dir = combo / 3, r = combo % 3;
    const float* Whh = (dir ? Whh_b : Whh_f) + r * 512 * 128;
    __shared__ float h[128];
    int u = threadIdx.x;
    const float* z = zxq + (size_t)(combo * NQ + q) * 512;
    float zi0 = z[u], zf0 = z[128 + u], zg0 = z[256 + u], zo0 = z[384 + u];
    const float* Wi = Whh + u * 128;
    const float* Wf = Whh + (128 + u) * 128;
    const float* Wg = Whh + (256 + u) * 128;
    const float* Wo = Whh + (384 + u) * 128;
    float c = 0.f;
    h[u] = 0.f;
    for (int s = 0; s < 3; ++s) {
        __syncthreads();
        float a0 = 0.f, a1 = 0.f, a2 = 0.f, a3 = 0.f;
        for (int d = 0; d < 128; ++d) {
            float hv = h[d];
            a0 = fmaf(hv, Wi[d], a0);
            a1 = fmaf(hv, Wf[d], a1);
            a2 = fmaf(hv, Wg[d], a2);
            a3 = fmaf(hv, Wo[d], a3);
        }
        float ig = 1.f / (1.f + expf(-(zi0 + a0)));
        float fg = 1.f / (1.f + expf(-(zf0 + a1)));
        float gg = tanhf(zg0 + a2);
        float og = 1.f / (1.f + expf(-(zo0 + a3)));
        c = fg * c + ig * gg;
        float hn = og * tanhf(c);
        __syncthreads();
        h[u] = hn;
        hq[(size_t)((combo * 3 + s) * NQ + q) * 128 + u] = hn;
    }
}

__global__ void attnq_kernel(const float* __restrict__ hq, const float* __restrict__ W0,
                             const float* __restrict__ b0, float* __restrict__ attnq) {
    int r = blockIdx.x / 3, t = blockIdx.x % 3;
    __shared__ float W0s[256 * 13];
    for (int idx = threadIdx.x; idx < 256 * 13; idx += 32) W0s[idx] = W0[idx];
    __syncthreads();
    int q = threadIdx.x;
    if (q >= NQ) return;
    float acc[13];
    for (int k = 0; k < 13; ++k) acc[k] = b0[k];
    const float* hf = hq + (size_t)(((0 * 3 + r) * 3 + t) * NQ + q) * 128;
    const float* hb = hq + (size_t)(((1 * 3 + r) * 3 + (2 - t)) * NQ + q) * 128;
    for (int u = 0; u < 128; ++u) {
        float v = hf[u];
        for (int k = 0; k < 13; ++k) acc[k] = fmaf(v, W0s[u * 13 + k], acc[k]);
    }
    for (int u = 0; u < 128; ++u) {
        float v = hb[u];
        for (int k = 0; k < 13; ++k) acc[k] = fmaf(v, W0s[(128 + u) * 13 + k], acc[k]);
    }
    float m = acc[0];
    for (int k = 1; k < 13; ++k) m = fmaxf(m, acc[k]);
    float e[13];
    float sum = 0.f;
    for (int k = 0; k < 13; ++k) { e[k] = expf(acc[k] - m); sum += e[k]; }
    float inv = 1.f / sum;
    float* ao = attnq + (size_t)(r * 3 + t) * 13 * NQ;
    for (int k = 0; k < 13; ++k) ao[k * NQ + q] = e[k] * inv;
}

__global__ void expand_kernel(const int* __restrict__ queries, const float* __restrict__ attnq,
                              float* __restrict__ attn) {
    __shared__ int qs[128];
    if (threadIdx.x < 128) qs[threadIdx.x] = queries[threadIdx.x];
    __syncthreads();
    for (int idx = threadIdx.x; idx < 9 * 13 * 128; idx += 256) {
        int b = idx & 127, kk = idx >> 7;
        attn[idx] = attnq[kk * NQ + qs[b]];
    }
}

// ---------------- steps 0+1, sparse expansion; writes pass-major mem[r][p][j][c] ----------------
__global__ void fused01_kernel(const int* __restrict__ heads, const float* __restrict__ attn,
                               const int* __restrict__ rpS, const int2* __restrict__ edgesS,
                               float* __restrict__ mem2) {
    int r = blockIdx.y;
    int b = blockIdx.x;
    __shared__ float c0s[13], c1s[13];
    if (threadIdx.x < 13) {
        c0s[threadIdx.x] = attn[(size_t)((r * 3 + 0) * 13 + threadIdx.x) * 128 + b];
        c1s[threadIdx.x] = attn[(size_t)((r * 3 + 1) * 13 + threadIdx.x) * 128 + b];
    }
    __syncthreads();
    int h = heads[b];
    int beg = rpS[h], end = rpS[h + 1];
    int nE = end - beg + 1;
    float* mem = mem2 + ((size_t)(r * NPASS + (b >> 4)) * NENT) * CP + (b & 15);
    for (int ent = threadIdx.x; ent < nE; ent += 128) {
        int i; float wv;
        if (ent == 0) { i = h; wv = c0s[12]; }
        else {
            int2 e = edgesS[beg + ent - 1];
            i = e.x & 0xFFFF;
            wv = __int_as_float(e.y) * c0s[e.x >> 16];
        }
        atomicAdd(&mem[(size_t)i * CP], c1s[12] * wv);
        int fb = rpS[i], fe = rpS[i + 1];
        for (int f = fb; f < fe; ++f) {
            int2 e2 = edgesS[f];
            atomicAdd(&mem[(size_t)(e2.x & 0xFFFF) * CP],
                      __int_as_float(e2.y) * c1s[e2.x >> 16] * wv);
        }
    }
}

// ---------------- step 2: dense gather; XCD-pinned pass; 16 edge-slots x float4 cols ----------------
__global__ __launch_bounds__(256) void dense_kernel(const float* __restrict__ attn,
                                                    const int* __restrict__ rpD,
                                                    const int2* __restrict__ edgesD,
                                                    const float* __restrict__ in,
                                                    float* __restrict__ out,
                                                    float* __restrict__ normv) {
    int p = blockIdx.x;   // pass = XCD (linear-id % 8 round-robin)
    int r = blockIdx.z;
    __shared__ int2 ebuf[2][CHUNK];
    __shared__ __align__(16) float cs[13 * 20];   // stride 20 floats: rows 16B-aligned
    __shared__ float npart[4][16];
    int tid = threadIdx.x;
    if (tid < 13 * 16) {
        int op = tid >> 4, c0 = tid & 15;
        cs[op * 20 + c0] = attn[(size_t)((r * 3 + 2) * 13 + op) * 128 + p * CP + c0];
    }
    int wave = tid >> 6, lane = tid & 63;
    int slot = lane >> 2;        // 16 edge slots
    int cq4 = (lane & 3) * 4;    // 4 cols per lane
    int j0 = blockIdx.y * 32;
    const float* inr = in + (size_t)(r * NPASS + p) * NENT * CP;
    float* outr = out + (size_t)(r * NPASS + p) * NENT * CP;
    int jw = j0 + wave * 8;
    int rb[9];
#pragma unroll
    for (int i = 0; i < 9; ++i) rb[i] = rpD[jw + i];
    int ebase = rpD[j0] & ~1;
    int kend = rpD[j0 + 32];
    int nch = (kend - ebase + CHUNK - 1) / CHUNK;

    auto stage = [&](int buf, int bb) {
        int ia = bb + tid * 2;       if (ia > NTOT - 2) ia = NTOT - 2;
        int ib = bb + 512 + tid * 2; if (ib > NTOT - 2) ib = NTOT - 2;
        gld16(&edgesD[ia], &ebuf[buf][wave * 128]);
        gld16(&edgesD[ib], &ebuf[buf][512 + wave * 128]);
    };

    stage(0, ebase);
    v4f acc[8];
#pragma unroll
    for (int i = 0; i < 8; ++i) acc[i] = (v4f)0.f;
    for (int ch = 0; ch < nch; ++ch) {
        __syncthreads();   // buf[ch&1] staged (vmcnt drained); prior reads of other buf done
        if (ch + 1 < nch) stage((ch + 1) & 1, ebase + (ch + 1) * CHUNK);
        int cb = ebase + ch * CHUNK;
        int ce = min(cb + CHUNK, kend);
        const int2* lb = ebuf[ch & 1];
#pragma unroll
        for (int rr = 0; rr < 8; ++rr) {
            int lo = max(rb[rr], cb) + slot;
            int hi = min(rb[rr + 1], ce);
            v4f a = acc[rr];
            for (int i = lo; i < hi; i += 16) {
                int2 ed = lb[i - cb];
                v4f cc = *(const v4f*)&cs[(ed.x >> 16) * 20 + cq4];
                v4f mm = *(const v4f*)(inr + (size_t)(ed.x & 0xFFFF) * CP + cq4);
                float v = __int_as_float(ed.y);
                a += (v * cc) * mm;
            }
            acc[rr] = a;
        }
    }
    v4f cid = *(const v4f*)&cs[12 * 20 + cq4];
    v4f rsum = (v4f)0.f;
#pragma unroll
    for (int rr = 0; rr < 8; ++rr) {
        v4f red = acc[rr];
        red += shfl_xor4(red, 4);
        red += shfl_xor4(red, 8);
        red += shfl_xor4(red, 16);
        red += shfl_xor4(red, 32);
        if (slot == 0) {
            int j = jw + rr;
            v4f mi = *(const v4f*)(inr + (size_t)j * CP + cq4);
            v4f res = cid * mi + red;
            __builtin_nontemporal_store(res, (v4f*)(outr + (size_t)j * CP + cq4));
            rsum += res;
        }
    }
    if (slot == 0) *(v4f*)&npart[wave][cq4] = rsum;
    __syncthreads();
    if (tid < 16) {
        float s = npart[0][tid] + npart[1][tid] + npart[2][tid] + npart[3][tid];
        atomicAdd(&normv[r * 128 + p * CP + tid], s);
    }
}

// ---------------- epilogue ----------------
__global__ void rnorm_kernel(const float* __restrict__ normv, float* __restrict__ rnormv) {
    int i = threadIdx.x;
    rnormv[i] = 1.f / fmaxf(normv[i], 1e-20f);
}

__global__ void final_kernel(const float* __restrict__ mem3, const float* __restrict__ rnormv,
                             float* __restrict__ out) {
    __shared__ float tile[32 * 129];
    __shared__ float rn[384];
    for (int idx = threadIdx.x; idx < 384; idx += 256) rn[idx] = rnormv[idx];
    __syncthreads();
    int j0 = blockIdx.x * 32;
    for (int p = 0; p < NPASS; ++p) {
        for (int it = 0; it < 2; ++it) {
            int lin = it * 256 + threadIdx.x;
            int jj = lin >> 4, c = lin & 15;
            int b = p * CP + c;
            float s = 0.f;
            for (int r = 0; r < 3; ++r)
                s += mem3[((size_t)(r * NPASS + p) * NENT + j0 + jj) * CP + c] * rn[r * 128 + b];
            tile[jj * 129 + b] = s;
        }
    }
    __syncthreads();
    for (int it = 0; it < 16; ++it) {
        int lin = it * 256 + threadIdx.x;
        int b = lin >> 5, jj = lin & 31;
        out[(size_t)b * NENT + j0 + jj] = tile[jj * 129 + b];
    }
}

extern "C" void kernel_launch(void* const* d_in, const int* in_sizes, int n_in,
                              void* d_out, int out_size, void* d_ws, size_t ws_size,
                              hipStream_t stream) {
    const int*   queries  = (const int*)d_in[0];
    const int*   heads    = (const int*)d_in[1];
    const int*   edge_src = (const int*)d_in[2];
    const int*   edge_dst = (const int*)d_in[3];
    const float* edge_val = (const float*)d_in[4];
    const float* emb      = (const float*)d_in[5];
    const float* Wih_f    = (const float*)d_in[6];
    const float* Whh_f    = (const float*)d_in[7];
    const float* bih_f    = (const float*)d_in[8];
    const float* bhh_f    = (const float*)d_in[9];
    const float* Wih_b    = (const float*)d_in[10];
    const float* Whh_b    = (const float*)d_in[11];
    const float* bih_b    = (const float*)d_in[12];
    const float* bhh_b    = (const float*)d_in[13];
    const float* W0       = (const float*)d_in[14];
    const float* b0       = (const float*)d_in[15];
    float* out = (float*)d_out;

    char* w = (char*)d_ws;
    size_t off = 0;
    auto alloc = [&](size_t bytes) -> void* {
        off = (off + 255) & ~(size_t)255;
        void* p = w + off;
        off += bytes;
        return p;
    };
    float* attnq  = (float*)alloc((size_t)9 * 13 * NQ * sizeof(float));
    float* attn   = (float*)alloc((size_t)9 * 13 * 128 * sizeof(float));
    float* zxq    = (float*)alloc((size_t)6 * NQ * 512 * sizeof(float));
    float* hq     = (float*)alloc((size_t)6 * 3 * NQ * 128 * sizeof(float));
    unsigned* bmH = (unsigned*)alloc(1250 * sizeof(unsigned));
    unsigned* bm2 = (unsigned*)alloc(1250 * sizeof(unsigned));
    int*   rp2    = (int*)alloc((size_t)2 * (NENT + 1) * sizeof(int));
    int*   rp4    = (int*)alloc((size_t)2 * NENT * 4 * sizeof(int));
    int*   cnt4   = (int*)alloc((size_t)2 * NENT * 4 * sizeof(int));
    int2*  edgesS = (int2*)alloc((size_t)NTOT * sizeof(int2));
    int2*  edgesD = (int2*)alloc((size_t)NTOT * sizeof(int2));
    float* mem2   = (float*)alloc((size_t)NRANK * NENT * NB * sizeof(float));
    float* mem3   = (float*)alloc((size_t)NRANK * NENT * NB * sizeof(float));
    float* normv  = (float*)alloc((size_t)NRANK * NB * sizeof(float));
    float* rnormv = (float*)alloc((size_t)NRANK * NB * sizeof(float));

    int* rpS = rp2;
    int* rpD = rp2 + (NENT + 1);
    int* rp4S = rp4;
    int* rp4D = rp4 + NENT * 4;
    int* cnt4S = cnt4;
    int* cnt4D = cnt4 + NENT * 4;

    int histGrid = (NTOT + 255) / 256;

    // bitmaps: heads, heads ∪ N_out(heads)
    hipMemsetAsync(bmH, 0, 2 * 1250 * sizeof(unsigned), stream);  // bmH+bm2 contiguous
    headmark_kernel<<<1, 128, 0, stream>>>(heads, bmH, bm2);
    mark2_kernel<<<histGrid, 256, 0, stream>>>(edge_src, edge_dst, bmH, bm2);

    // CSR build (dst full; src gated on bm2)
    hipMemsetAsync(cnt4, 0, 2 * NENT * 4 * sizeof(int), stream);
    hist2_kernel<<<histGrid, 256, 0, stream>>>(edge_src, edge_dst, bm2, cnt4S, cnt4D);
    scan2_kernel<<<2, 1024, 0, stream>>>(cnt4, rp2, rp4);
    hipMemsetAsync(cnt4, 0, 2 * NENT * 4 * sizeof(int), stream);
    scatter2_kernel<<<histGrid, 256, 0, stream>>>(edge_src, edge_dst, edge_val, bm2,
                                                  rp4S, rp4D, cnt4S, cnt4D, edgesS, edgesD);

    // LSTM + attention (deduped over 24 queries)
    zxq_kernel<<<6 * NQ, 128, 0, stream>>>(emb, Wih_f, bih_f, bhh_f, Wih_b, bih_b, bhh_b, zxq);
    lstmq_kernel<<<6 * NQ, 128, 0, stream>>>(Whh_f, Whh_b, zxq, hq);
    attnq_kernel<<<9, 32, 0, stream>>>(hq, W0, b0, attnq);
    expand_kernel<<<1, 256, 0, stream>>>(queries, attnq, attn);

    // steps 0+1 sparse, step 2 dense (norm fused into dense)
    hipMemsetAsync(mem2, 0, (size_t)NRANK * NENT * NB * sizeof(float), stream);
    hipMemsetAsync(normv, 0, NRANK * NB * sizeof(float), stream);
    {
        dim3 g(NB, NRANK);
        fused01_kernel<<<g, 128, 0, stream>>>(heads, attn, rpS, edgesS, mem2);
    }
    {
        dim3 g(NPASS, NENT / 32, NRANK);
        dense_kernel<<<g, 256, 0, stream>>>(attn, rpD, edgesD, mem2, mem3, normv);
    }

    // epilogue
    rnorm_kernel<<<1, NRANK * NB, 0, stream>>>(normv, rnormv);
    final_kernel<<<NENT / 32, 256, 0, stream>>>(mem3, rnormv, out);
}

// Round 6
// 1282.809 us; speedup vs baseline: 2.6494x; 1.2702x over previous
//
#include <hip/hip_runtime.h>

#define NENT 40000
#define NB 128
#define NQ 24
#define NOPS 12
#define EPO 300000
#define NTOT (NOPS * EPO)
#define NRANK 3
#define NPASS 8
#define CP 16       // batch columns per pass
#define ECAP 160    // ELL row capacity (Poisson(90) max over 40K rows << 160)

typedef float v4f __attribute__((ext_vector_type(4)));

__device__ __forceinline__ v4f shfl_xor4(v4f x, int m) {
    v4f r;
    r.x = __shfl_xor(x.x, m);
    r.y = __shfl_xor(x.y, m);
    r.z = __shfl_xor(x.z, m);
    r.w = __shfl_xor(x.w, m);
    return r;
}

__device__ __forceinline__ bool bittest(const unsigned* bm, int i) {
    return (bm[i >> 5] >> (i & 31)) & 1u;
}

// ---------------- bitmaps: heads and heads ∪ N_out(heads) ----------------
__global__ void headmark_kernel(const int* __restrict__ heads, unsigned* __restrict__ bmH,
                                unsigned* __restrict__ bm2) {
    int h = heads[threadIdx.x];
    atomicOr(&bmH[h >> 5], 1u << (h & 31));
    atomicOr(&bm2[h >> 5], 1u << (h & 31));
}

__global__ void mark2_kernel(const int* __restrict__ src, const int* __restrict__ dst,
                             const unsigned* __restrict__ bmH, unsigned* __restrict__ bm2) {
    int i = blockIdx.x * 256 + threadIdx.x;
    if (i < NTOT) {
        int s = src[i];
        if (bittest(bmH, s)) {
            int d = dst[i];
            atomicOr(&bm2[d >> 5], 1u << (d & 31));
        }
    }
}

// ---------------- single-pass ELL build: dst always; src gated on bm2 ----------------
__global__ void build_ell_kernel(const int* __restrict__ src, const int* __restrict__ dst,
                                 const float* __restrict__ val, const unsigned* __restrict__ bm2,
                                 int* __restrict__ fillD, int* __restrict__ fillS,
                                 int2* __restrict__ eD, int2* __restrict__ eS) {
    int i = blockIdx.x * 256 + threadIdx.x;
    if (i >= NTOT) return;
    int s = src[i], d = dst[i];
    int op = i / EPO;   // compile-time magic-mul
    int v = __float_as_int(val[i]);
    int pd = atomicAdd(&fillD[d], 1);
    eD[(size_t)d * ECAP + pd] = make_int2(s | (op << 16), v);
    if (bittest(bm2, s)) {
        int ps = atomicAdd(&fillS[s], 1);
        eS[(size_t)s * ECAP + ps] = make_int2(d | (op << 16), v);
    }
}

// ---------------- LSTM (deduped over 24 distinct query values) ----------------
__global__ void zxq_kernel(const float* __restrict__ emb,
                           const float* __restrict__ Wih_f, const float* __restrict__ bih_f,
                           const float* __restrict__ bhh_f,
                           const float* __restrict__ Wih_b, const float* __restrict__ bih_b,
                           const float* __restrict__ bhh_b,
                           float* __restrict__ zxq) {
    int combo = blockIdx.x / NQ;
    int q = blockIdx.x % NQ;
    int dir = combo / 3, r = combo % 3;
    const float* Wih = (dir ? Wih_b : Wih_f) + r * 512 * 128;
    const float* bih = (dir ? bih_b : bih_f) + r * 512;
    const float* bhh = (dir ? bhh_b : bhh_f) + r * 512;
    __shared__ float x[128];
    int u = threadIdx.x;
    x[u] = emb[q * 128 + u];
    __syncthreads();
    const float* W0p = Wih + u * 128;
    const float* W1p = Wih + (128 + u) * 128;
    const float* W2p = Wih + (256 + u) * 128;
    const float* W3p = Wih + (384 + u) * 128;
    float a0 = 0.f, a1 = 0.f, a2 = 0.f, a3 = 0.f;
    for (int d = 0; d < 128; ++d) {
        float xv = x[d];
        a0 = fmaf(xv, W0p[d], a0);
        a1 = fmaf(xv, W1p[d], a1);
        a2 = fmaf(xv, W2p[d], a2);
        a3 = fmaf(xv, W3p[d], a3);
    }
    float* o = zxq + (size_t)(combo * NQ + q) * 512;
    o[u]       = a0 + bih[u]       + bhh[u];
    o[128 + u] = a1 + bih[128 + u] + bhh[128 + u];
    o[256 + u] = a2 + bih[256 + u] + bhh[256 + u];
    o[384 + u] = a3 + bih[384 + u] + bhh[384 + u];
}

__global__ void lstmq_kernel(const float* __restrict__ Whh_f, const float* __restrict__ Whh_b,
                             const float* __restrict__ zxq, float* __restrict__ hq) {
    int combo = blockIdx.x / NQ;
    int q = blockIdx.x % NQ;
    int dir = combo / 3, r = combo % 3;
    const float* Whh = (dir ? Whh_b : Whh_f) + r * 512 * 128;
    __shared__ float h[128];
    int u = threadIdx.x;
    const float* z = zxq + (size_t)(combo * NQ + q) * 512;
    float zi0 = z[u], zf0 = z[128 + u], zg0 = z[256 + u], zo0 = z[384 + u];
    const float* Wi = Whh + u * 128;
    const float* Wf = Whh + (128 + u) * 128;
    const float* Wg = Whh + (256 + u) * 128;
    const float* Wo = Whh + (384 + u) * 128;
    float c = 0.f;
    h[u] = 0.f;
    for (int s = 0; s < 3; ++s) {
        __syncthreads();
        float a0 = 0.f, a1 = 0.f, a2 = 0.f, a3 = 0.f;
        for (int d = 0; d < 128; ++d) {
            float hv = h[d];
            a0 = fmaf(hv, Wi[d], a0);
            a1 = fmaf(hv, Wf[d], a1);
            a2 = fmaf(hv, Wg[d], a2);
            a3 = fmaf(hv, Wo[d], a3);
        }
        float ig = 1.f / (1.f + expf(-(zi0 + a0)));
        float fg = 1.f / (1.f + expf(-(zf0 + a1)));
        float gg = tanhf(zg0 + a2);
        float og = 1.f / (1.f + expf(-(zo0 + a3)));
        c = fg * c + ig * gg;
        float hn = og * tanhf(c);
        __syncthreads();
        h[u] = hn;
        hq[(size_t)((combo * 3 + s) * NQ + q) * 128 + u] = hn;
    }
}

__global__ void attnq_kernel(const float* __restrict__ hq, const float* __restrict__ W0,
                             const float* __restrict__ b0, float* __restrict__ attnq) {
    int r = blockIdx.x / 3, t = blockIdx.x % 3;
    __shared__ float W0s[256 * 13];
    for (int idx = threadIdx.x; idx < 256 * 13; idx += 32) W0s[idx] = W0[idx];
    __syncthreads();
    int q = threadIdx.x;
    if (q >= NQ) return;
    float acc[13];
    for (int k = 0; k < 13; ++k) acc[k] = b0[k];
    const float* hf = hq + (size_t)(((0 * 3 + r) * 3 + t) * NQ + q) * 128;
    const float* hb = hq + (size_t)(((1 * 3 + r) * 3 + (2 - t)) * NQ + q) * 128;
    for (int u = 0; u < 128; ++u) {
        float v = hf[u];
        for (int k = 0; k < 13; ++k) acc[k] = fmaf(v, W0s[u * 13 + k], acc[k]);
    }
    for (int u = 0; u < 128; ++u) {
        float v = hb[u];
        for (int k = 0; k < 13; ++k) acc[k] = fmaf(v, W0s[(128 + u) * 13 + k], acc[k]);
    }
    float m = acc[0];
    for (int k = 1; k < 13; ++k) m = fmaxf(m, acc[k]);
    float e[13];
    float sum = 0.f;
    for (int k = 0; k < 13; ++k) { e[k] = expf(acc[k] - m); sum += e[k]; }
    float inv = 1.f / sum;
    float* ao = attnq + (size_t)(r * 3 + t) * 13 * NQ;
    for (int k = 0; k < 13; ++k) ao[k * NQ + q] = e[k] * inv;
}

__global__ void expand_kernel(const int* __restrict__ queries, const float* __restrict__ attnq,
                              float* __restrict__ attn) {
    __shared__ int qs[128];
    if (threadIdx.x < 128) qs[threadIdx.x] = queries[threadIdx.x];
    __syncthreads();
    for (int idx = threadIdx.x; idx < 9 * 13 * 128; idx += 256) {
        int b = idx & 127, kk = idx >> 7;
        attn[idx] = attnq[kk * NQ + qs[b]];
    }
}

// ---------------- steps 0+1, sparse expansion over ELL-S; writes pass-major mem[r][p][j][c] ----------------
__global__ void fused01_kernel(const int* __restrict__ heads, const float* __restrict__ attn,
                               const int* __restrict__ fillS, const int2* __restrict__ eS,
                               float* __restrict__ mem2) {
    int r = blockIdx.y;
    int b = blockIdx.x;
    __shared__ float c0s[13], c1s[13];
    if (threadIdx.x < 13) {
        c0s[threadIdx.x] = attn[(size_t)((r * 3 + 0) * 13 + threadIdx.x) * 128 + b];
        c1s[threadIdx.x] = attn[(size_t)((r * 3 + 1) * 13 + threadIdx.x) * 128 + b];
    }
    __syncthreads();
    int h = heads[b];
    int lenH = fillS[h];
    float* mem = mem2 + ((size_t)(r * NPASS + (b >> 4)) * NENT) * CP + (b & 15);
    for (int ent = threadIdx.x; ent < lenH + 1; ent += 128) {
        int i; float wv;
        if (ent == 0) { i = h; wv = c0s[12]; }
        else {
            int2 e = eS[(size_t)h * ECAP + ent - 1];
            i = e.x & 0xFFFF;
            wv = __int_as_float(e.y) * c0s[e.x >> 16];
        }
        atomicAdd(&mem[(size_t)i * CP], c1s[12] * wv);
        int lenI = fillS[i];
        const int2* ei = eS + (size_t)i * ECAP;
        for (int f = 0; f < lenI; ++f) {
            int2 e2 = ei[f];
            atomicAdd(&mem[(size_t)(e2.x & 0xFFFF) * CP],
                      __int_as_float(e2.y) * c1s[e2.x >> 16] * wv);
        }
    }
}

// ---------------- step 2: dense gather; XCD-pinned pass; direct loads, unroll-4 MLP ----------------
__global__ __launch_bounds__(256) void dense_kernel(const float* __restrict__ attn,
                                                    const int* __restrict__ fillD,
                                                    const int2* __restrict__ edgesD,
                                                    const float* __restrict__ in,
                                                    float* __restrict__ out,
                                                    float* __restrict__ normv) {
    int p = blockIdx.x;   // pass = XCD (linear-id % 8 round-robin)
    int r = blockIdx.z;
    __shared__ __align__(16) float cs[13 * 20];   // stride 20 floats: rows 16B-aligned
    __shared__ float npart[4][16];
    int tid = threadIdx.x;
    if (tid < 13 * 16) {
        int op = tid >> 4, c0 = tid & 15;
        cs[op * 20 + c0] = attn[(size_t)((r * 3 + 2) * 13 + op) * 128 + p * CP + c0];
    }
    __syncthreads();
    int wave = tid >> 6, lane = tid & 63;
    int slot = lane >> 2;        // 16 edge slots
    int cq4 = (lane & 3) * 4;    // 4 cols per lane
    int jw = blockIdx.y * 32 + wave * 8;
    const float* inr = in + (size_t)(r * NPASS + p) * NENT * CP;
    float* outr = out + (size_t)(r * NPASS + p) * NENT * CP;
    int lens[8];
#pragma unroll
    for (int i = 0; i < 8; ++i) lens[i] = fillD[jw + i];
    v4f cid = *(const v4f*)&cs[12 * 20 + cq4];
    v4f rsum = (v4f)0.f;
#pragma unroll
    for (int rr = 0; rr < 8; ++rr) {
        int j = jw + rr;
        int len = lens[rr];
        const int2* ed = edgesD + (size_t)j * ECAP;
        v4f a = (v4f)0.f;
        for (int i = slot; i < len; i += 64) {
            int i1 = i + 16, i2 = i + 32, i3 = i + 48;
            bool m1 = i1 < len, m2 = i2 < len, m3 = i3 < len;
            int2 e0 = ed[i];
            int2 e1 = ed[m1 ? i1 : i];
            int2 e2 = ed[m2 ? i2 : i];
            int2 e3 = ed[m3 ? i3 : i];
            v4f g0 = *(const v4f*)(inr + (size_t)(e0.x & 0xFFFF) * CP + cq4);
            v4f g1 = *(const v4f*)(inr + (size_t)(e1.x & 0xFFFF) * CP + cq4);
            v4f g2 = *(const v4f*)(inr + (size_t)(e2.x & 0xFFFF) * CP + cq4);
            v4f g3 = *(const v4f*)(inr + (size_t)(e3.x & 0xFFFF) * CP + cq4);
            v4f c0 = *(const v4f*)&cs[(e0.x >> 16) * 20 + cq4];
            v4f c1 = *(const v4f*)&cs[(e1.x >> 16) * 20 + cq4];
            v4f c2 = *(const v4f*)&cs[(e2.x >> 16) * 20 + cq4];
            v4f c3 = *(const v4f*)&cs[(e3.x >> 16) * 20 + cq4];
            float v0 = __int_as_float(e0.y);
            float v1 = m1 ? __int_as_float(e1.y) : 0.f;
            float v2 = m2 ? __int_as_float(e2.y) : 0.f;
            float v3 = m3 ? __int_as_float(e3.y) : 0.f;
            a += (v0 * c0) * g0;
            a += (v1 * c1) * g1;
            a += (v2 * c2) * g2;
            a += (v3 * c3) * g3;
        }
        a += shfl_xor4(a, 4);
        a += shfl_xor4(a, 8);
        a += shfl_xor4(a, 16);
        a += shfl_xor4(a, 32);
        if (slot == 0) {
            v4f mi = *(const v4f*)(inr + (size_t)j * CP + cq4);
            v4f res = cid * mi + a;
            __builtin_nontemporal_store(res, (v4f*)(outr + (size_t)j * CP + cq4));
            rsum += res;
        }
    }
    if (slot == 0) *(v4f*)&npart[wave][cq4] = rsum;
    __syncthreads();
    if (tid < 16) {
        float s = npart[0][tid] + npart[1][tid] + npart[2][tid] + npart[3][tid];
        atomicAdd(&normv[r * 128 + p * CP + tid], s);
    }
}

// ---------------- epilogue ----------------
__global__ void rnorm_kernel(const float* __restrict__ normv, float* __restrict__ rnormv) {
    int i = threadIdx.x;
    rnormv[i] = 1.f / fmaxf(normv[i], 1e-20f);
}

__global__ void final_kernel(const float* __restrict__ mem3, const float* __restrict__ rnormv,
                             float* __restrict__ out) {
    __shared__ float tile[32 * 129];
    __shared__ float rn[384];
    for (int idx = threadIdx.x; idx < 384; idx += 256) rn[idx] = rnormv[idx];
    __syncthreads();
    int j0 = blockIdx.x * 32;
    for (int p = 0; p < NPASS; ++p) {
        for (int it = 0; it < 2; ++it) {
            int lin = it * 256 + threadIdx.x;
            int jj = lin >> 4, c = lin & 15;
            int b = p * CP + c;
            float s = 0.f;
            for (int r = 0; r < 3; ++r)
                s += mem3[((size_t)(r * NPASS + p) * NENT + j0 + jj) * CP + c] * rn[r * 128 + b];
            tile[jj * 129 + b] = s;
        }
    }
    __syncthreads();
    for (int it = 0; it < 16; ++it) {
        int lin = it * 256 + threadIdx.x;
        int b = lin >> 5, jj = lin & 31;
        out[(size_t)b * NENT + j0 + jj] = tile[jj * 129 + b];
    }
}

extern "C" void kernel_launch(void* const* d_in, const int* in_sizes, int n_in,
                              void* d_out, int out_size, void* d_ws, size_t ws_size,
                              hipStream_t stream) {
    const int*   queries  = (const int*)d_in[0];
    const int*   heads    = (const int*)d_in[1];
    const int*   edge_src = (const int*)d_in[2];
    const int*   edge_dst = (const int*)d_in[3];
    const float* edge_val = (const float*)d_in[4];
    const float* emb      = (const float*)d_in[5];
    const float* Wih_f    = (const float*)d_in[6];
    const float* Whh_f    = (const float*)d_in[7];
    const float* bih_f    = (const float*)d_in[8];
    const float* bhh_f    = (const float*)d_in[9];
    const float* Wih_b    = (const float*)d_in[10];
    const float* Whh_b    = (const float*)d_in[11];
    const float* bih_b    = (const float*)d_in[12];
    const float* bhh_b    = (const float*)d_in[13];
    const float* W0       = (const float*)d_in[14];
    const float* b0       = (const float*)d_in[15];
    float* out = (float*)d_out;

    char* w = (char*)d_ws;
    size_t off = 0;
    auto alloc = [&](size_t bytes) -> void* {
        off = (off + 255) & ~(size_t)255;
        void* p = w + off;
        off += bytes;
        return p;
    };
    float* attnq  = (float*)alloc((size_t)9 * 13 * NQ * sizeof(float));
    float* attn   = (float*)alloc((size_t)9 * 13 * 128 * sizeof(float));
    float* zxq    = (float*)alloc((size_t)6 * NQ * 512 * sizeof(float));
    float* hq     = (float*)alloc((size_t)6 * 3 * NQ * 128 * sizeof(float));
    // meta block (single memset): bmH | bm2 | fillD | fillS
    unsigned* bmH = (unsigned*)alloc((2 * 1250 + 2 * NENT) * sizeof(int));
    unsigned* bm2 = bmH + 1250;
    int* fillD    = (int*)(bm2 + 1250);
    int* fillS    = fillD + NENT;
    int2*  eD     = (int2*)alloc((size_t)NENT * ECAP * sizeof(int2));
    float* mem2   = (float*)alloc((size_t)NRANK * NENT * NB * sizeof(float));
    float* mem3   = (float*)alloc((size_t)NRANK * NENT * NB * sizeof(float));
    int2*  eS     = (int2*)mem3;   // alias: eS lifetime (build..fused01) ends before mem3's (dense..final)
    float* normv  = (float*)alloc((size_t)NRANK * NB * sizeof(float));
    float* rnormv = (float*)alloc((size_t)NRANK * NB * sizeof(float));

    int cooGrid = (NTOT + 255) / 256;

    // bitmaps + fills (one memset), then single-pass ELL build
    hipMemsetAsync(bmH, 0, (2 * 1250 + 2 * NENT) * sizeof(int), stream);
    headmark_kernel<<<1, 128, 0, stream>>>(heads, bmH, bm2);
    mark2_kernel<<<cooGrid, 256, 0, stream>>>(edge_src, edge_dst, bmH, bm2);
    build_ell_kernel<<<cooGrid, 256, 0, stream>>>(edge_src, edge_dst, edge_val, bm2,
                                                  fillD, fillS, eD, eS);

    // LSTM + attention (deduped over 24 queries)
    zxq_kernel<<<6 * NQ, 128, 0, stream>>>(emb, Wih_f, bih_f, bhh_f, Wih_b, bih_b, bhh_b, zxq);
    lstmq_kernel<<<6 * NQ, 128, 0, stream>>>(Whh_f, Whh_b, zxq, hq);
    attnq_kernel<<<9, 32, 0, stream>>>(hq, W0, b0, attnq);
    expand_kernel<<<1, 256, 0, stream>>>(queries, attnq, attn);

    // steps 0+1 sparse, step 2 dense (norm fused into dense)
    hipMemsetAsync(mem2, 0, (size_t)NRANK * NENT * NB * sizeof(float), stream);
    hipMemsetAsync(normv, 0, NRANK * NB * sizeof(float), stream);
    {
        dim3 g(NB, NRANK);
        fused01_kernel<<<g, 128, 0, stream>>>(heads, attn, fillS, eS, mem2);
    }
    {
        dim3 g(NPASS, NENT / 32, NRANK);
        dense_kernel<<<g, 256, 0, stream>>>(attn, fillD, eD, mem2, mem3, normv);
    }

    // epilogue
    rnorm_kernel<<<1, NRANK * NB, 0, stream>>>(normv, rnormv);
    final_kernel<<<NENT / 32, 256, 0, stream>>>(mem3, rnormv, out);
}

// Round 7
// 1267.219 us; speedup vs baseline: 2.6820x; 1.0123x over previous
//
#include <hip/hip_runtime.h>

#define NENT 40000
#define NB 128
#define NQ 24
#define NOPS 12
#define EPO 300000
#define NTOT (NOPS * EPO)
#define NRANK 3
#define NPASS 8
#define CP 16       // batch columns per pass
#define ECAP 160    // ELL row capacity (Poisson(90) max over 40K rows << 160)

typedef float v4f __attribute__((ext_vector_type(4)));

__device__ __forceinline__ v4f shfl_xor4(v4f x, int m) {
    v4f r;
    r.x = __shfl_xor(x.x, m);
    r.y = __shfl_xor(x.y, m);
    r.z = __shfl_xor(x.z, m);
    r.w = __shfl_xor(x.w, m);
    return r;
}

__device__ __forceinline__ bool bittest(const unsigned* bm, int i) {
    return (bm[i >> 5] >> (i & 31)) & 1u;
}

// ---------------- bitmaps: heads and heads ∪ N_out(heads) ----------------
__global__ void headmark_kernel(const int* __restrict__ heads, unsigned* __restrict__ bmH,
                                unsigned* __restrict__ bm2) {
    int h = heads[threadIdx.x];
    atomicOr(&bmH[h >> 5], 1u << (h & 31));
    atomicOr(&bm2[h >> 5], 1u << (h & 31));
}

__global__ void mark2_kernel(const int* __restrict__ src, const int* __restrict__ dst,
                             const unsigned* __restrict__ bmH, unsigned* __restrict__ bm2) {
    int i = blockIdx.x * 256 + threadIdx.x;
    if (i < NTOT) {
        int s = src[i];
        if (bittest(bmH, s)) {
            int d = dst[i];
            atomicOr(&bm2[d >> 5], 1u << (d & 31));
        }
    }
}

// ---------------- single-pass ELL build: dst always; src gated on bm2 ----------------
__global__ void build_ell_kernel(const int* __restrict__ src, const int* __restrict__ dst,
                                 const float* __restrict__ val, const unsigned* __restrict__ bm2,
                                 int* __restrict__ fillD, int* __restrict__ fillS,
                                 int2* __restrict__ eD, int2* __restrict__ eS) {
    int i = blockIdx.x * 256 + threadIdx.x;
    if (i >= NTOT) return;
    int s = src[i], d = dst[i];
    int op = i / EPO;   // compile-time magic-mul
    int v = __float_as_int(val[i]);
    int pd = atomicAdd(&fillD[d], 1);
    eD[(size_t)d * ECAP + pd] = make_int2(s | (op << 16), v);
    if (bittest(bm2, s)) {
        int ps = atomicAdd(&fillS[s], 1);
        eS[(size_t)s * ECAP + ps] = make_int2(d | (op << 16), v);
    }
}

// ---------------- LSTM (deduped over 24 distinct query values) ----------------
__global__ void zxq_kernel(const float* __restrict__ emb,
                           const float* __restrict__ Wih_f, const float* __restrict__ bih_f,
                           const float* __restrict__ bhh_f,
                           const float* __restrict__ Wih_b, const float* __restrict__ bih_b,
                           const float* __restrict__ bhh_b,
                           float* __restrict__ zxq) {
    int combo = blockIdx.x / NQ;
    int q = blockIdx.x % NQ;
    int dir = combo / 3, r = combo % 3;
    const float* Wih = (dir ? Wih_b : Wih_f) + r * 512 * 128;
    const float* bih = (dir ? bih_b : bih_f) + r * 512;
    const float* bhh = (dir ? bhh_b : bhh_f) + r * 512;
    __shared__ float x[128];
    int u = threadIdx.x;
    x[u] = emb[q * 128 + u];
    __syncthreads();
    const float* W0p = Wih + u * 128;
    const float* W1p = Wih + (128 + u) * 128;
    const float* W2p = Wih + (256 + u) * 128;
    const float* W3p = Wih + (384 + u) * 128;
    float a0 = 0.f, a1 = 0.f, a2 = 0.f, a3 = 0.f;
    for (int d = 0; d < 128; ++d) {
        float xv = x[d];
        a0 = fmaf(xv, W0p[d], a0);
        a1 = fmaf(xv, W1p[d], a1);
        a2 = fmaf(xv, W2p[d], a2);
        a3 = fmaf(xv, W3p[d], a3);
    }
    float* o = zxq + (size_t)(combo * NQ + q) * 512;
    o[u]       = a0 + bih[u]       + bhh[u];
    o[128 + u] = a1 + bih[128 + u] + bhh[128 + u];
    o[256 + u] = a2 + bih[256 + u] + bhh[256 + u];
    o[384 + u] = a3 + bih[384 + u] + bhh[384 + u];
}

__global__ void lstmq_kernel(const float* __restrict__ Whh_f, const float* __restrict__ Whh_b,
                             const float* __restrict__ zxq, float* __restrict__ hq) {
    int combo = blockIdx.x / NQ;
    int q = blockIdx.x % NQ;
    int dir = combo / 3, r = combo % 3;
    const float* Whh = (dir ? Whh_b : Whh_f) + r * 512 * 128;
    __shared__ float h[128];
    int u = threadIdx.x;
    const float* z = zxq + (size_t)(combo * NQ + q) * 512;
    float zi0 = z[u], zf0 = z[128 + u], zg0 = z[256 + u], zo0 = z[384 + u];
    const float* Wi = Whh + u * 128;
    const float* Wf = Whh + (128 + u) * 128;
    const float* Wg = Whh + (256 + u) * 128;
    const float* Wo = Whh + (384 + u) * 128;
    float c = 0.f;
    h[u] = 0.f;
    for (int s = 0; s < 3; ++s) {
        __syncthreads();
        float a0 = 0.f, a1 = 0.f, a2 = 0.f, a3 = 0.f;
        for (int d = 0; d < 128; ++d) {
            float hv = h[d];
            a0 = fmaf(hv, Wi[d], a0);
            a1 = fmaf(hv, Wf[d], a1);
            a2 = fmaf(hv, Wg[d], a2);
            a3 = fmaf(hv, Wo[d], a3);
        }
        float ig = 1.f / (1.f + expf(-(zi0 + a0)));
        float fg = 1.f / (1.f + expf(-(zf0 + a1)));
        float gg = tanhf(zg0 + a2);
        float og = 1.f / (1.f + expf(-(zo0 + a3)));
        c = fg * c + ig * gg;
        float hn = og * tanhf(c);
        __syncthreads();
        h[u] = hn;
        hq[(size_t)((combo * 3 + s) * NQ + q) * 128 + u] = hn;
    }
}

__global__ void attnq_kernel(const float* __restrict__ hq, const float* __restrict__ W0,
                             const float* __restrict__ b0, float* __restrict__ attnq) {
    int r = blockIdx.x / 3, t = blockIdx.x % 3;
    __shared__ float W0s[256 * 13];
    for (int idx = threadIdx.x; idx < 256 * 13; idx += 32) W0s[idx] = W0[idx];
    __syncthreads();
    int q = threadIdx.x;
    if (q >= NQ) return;
    float acc[13];
    for (int k = 0; k < 13; ++k) acc[k] = b0[k];
    const float* hf = hq + (size_t)(((0 * 3 + r) * 3 + t) * NQ + q) * 128;
    const float* hb = hq + (size_t)(((1 * 3 + r) * 3 + (2 - t)) * NQ + q) * 128;
    for (int u = 0; u < 128; ++u) {
        float v = hf[u];
        for (int k = 0; k < 13; ++k) acc[k] = fmaf(v, W0s[u * 13 + k], acc[k]);
    }
    for (int u = 0; u < 128; ++u) {
        float v = hb[u];
        for (int k = 0; k < 13; ++k) acc[k] = fmaf(v, W0s[(128 + u) * 13 + k], acc[k]);
    }
    float m = acc[0];
    for (int k = 1; k < 13; ++k) m = fmaxf(m, acc[k]);
    float e[13];
    float sum = 0.f;
    for (int k = 0; k < 13; ++k) { e[k] = expf(acc[k] - m); sum += e[k]; }
    float inv = 1.f / sum;
    float* ao = attnq + (size_t)(r * 3 + t) * 13 * NQ;
    for (int k = 0; k < 13; ++k) ao[k * NQ + q] = e[k] * inv;
}

__global__ void expand_kernel(const int* __restrict__ queries, const float* __restrict__ attnq,
                              float* __restrict__ attn) {
    __shared__ int qs[128];
    if (threadIdx.x < 128) qs[threadIdx.x] = queries[threadIdx.x];
    __syncthreads();
    for (int idx = threadIdx.x; idx < 9 * 13 * 128; idx += 256) {
        int b = idx & 127, kk = idx >> 7;
        attn[idx] = attnq[kk * NQ + qs[b]];
    }
}

// ---------------- steps 0+1, sparse expansion over ELL-S; writes pass-major mem[r][p][j][c] ----------------
__global__ void fused01_kernel(const int* __restrict__ heads, const float* __restrict__ attn,
                               const int* __restrict__ fillS, const int2* __restrict__ eS,
                               float* __restrict__ mem2) {
    int r = blockIdx.y;
    int b = blockIdx.x;
    __shared__ float c0s[13], c1s[13];
    if (threadIdx.x < 13) {
        c0s[threadIdx.x] = attn[(size_t)((r * 3 + 0) * 13 + threadIdx.x) * 128 + b];
        c1s[threadIdx.x] = attn[(size_t)((r * 3 + 1) * 13 + threadIdx.x) * 128 + b];
    }
    __syncthreads();
    int h = heads[b];
    int lenH = fillS[h];
    float* mem = mem2 + ((size_t)(r * NPASS + (b >> 4)) * NENT) * CP + (b & 15);
    for (int ent = threadIdx.x; ent < lenH + 1; ent += 128) {
        int i; float wv;
        if (ent == 0) { i = h; wv = c0s[12]; }
        else {
            int2 e = eS[(size_t)h * ECAP + ent - 1];
            i = e.x & 0xFFFF;
            wv = __int_as_float(e.y) * c0s[e.x >> 16];
        }
        atomicAdd(&mem[(size_t)i * CP], c1s[12] * wv);
        int lenI = fillS[i];
        const int2* ei = eS + (size_t)i * ECAP;
        for (int f = 0; f < lenI; ++f) {
            int2 e2 = ei[f];
            atomicAdd(&mem[(size_t)(e2.x & 0xFFFF) * CP],
                      __int_as_float(e2.y) * c1s[e2.x >> 16] * wv);
        }
    }
}

// ---------------- step 2: dense gather; XCD-pinned pass; 4-row interleave, deferred reduce ----------------
__global__ __launch_bounds__(256) void dense_kernel(const float* __restrict__ attn,
                                                    const int* __restrict__ fillD,
                                                    const int2* __restrict__ edgesD,
                                                    const float* __restrict__ in,
                                                    float* __restrict__ out,
                                                    float* __restrict__ normv) {
    int p = blockIdx.x;   // pass = XCD (linear-id % 8 round-robin)
    int r = blockIdx.z;
    __shared__ __align__(16) float cs[13 * 20];   // stride 20 floats: rows 16B-aligned
    __shared__ float npart[4][16];
    int tid = threadIdx.x;
    if (tid < 13 * 16) {
        int op = tid >> 4, c0 = tid & 15;
        cs[op * 20 + c0] = attn[(size_t)((r * 3 + 2) * 13 + op) * 128 + p * CP + c0];
    }
    __syncthreads();
    int wave = tid >> 6, lane = tid & 63;
    int slot = lane >> 2;        // 16 edge slots
    int cq4 = (lane & 3) * 4;    // 4 cols per lane
    int jw = blockIdx.y * 16 + wave * 4;   // 4 rows per wave
    const float* inr = in + (size_t)(r * NPASS + p) * NENT * CP;
    float* outr = out + (size_t)(r * NPASS + p) * NENT * CP;
    int lens[4];
    const int2* edp[4];
#pragma unroll
    for (int t = 0; t < 4; ++t) {
        lens[t] = fillD[jw + t];
        edp[t] = edgesD + (size_t)(jw + t) * ECAP;
    }
    int maxlen = max(max(lens[0], lens[1]), max(lens[2], lens[3]));
    v4f acc[4];
#pragma unroll
    for (int t = 0; t < 4; ++t) acc[t] = (v4f)0.f;

    // interleaved: 8 independent edge loads + 8 independent gathers per iteration
    for (int base = 0; base < maxlen; base += 32) {
        int2 e[8];
        bool m[8];
#pragma unroll
        for (int t = 0; t < 4; ++t) {
            int ia = base + slot;
            int ib = base + 16 + slot;
            m[t]     = ia < lens[t];
            m[4 + t] = ib < lens[t];
            e[t]     = edp[t][m[t] ? ia : 0];
            e[4 + t] = edp[t][m[4 + t] ? ib : 0];
        }
        v4f g[8];
#pragma unroll
        for (int u = 0; u < 8; ++u)
            g[u] = *(const v4f*)(inr + (size_t)(e[u].x & 0xFFFF) * CP + cq4);
#pragma unroll
        for (int u = 0; u < 8; ++u) {
            v4f cc = *(const v4f*)&cs[(e[u].x >> 16) * 20 + cq4];
            float v = m[u] ? __int_as_float(e[u].y) : 0.f;
            acc[u & 3] += (v * cc) * g[u];
        }
    }

    v4f cid = *(const v4f*)&cs[12 * 20 + cq4];
    v4f rsum = (v4f)0.f;
#pragma unroll
    for (int t = 0; t < 4; ++t) {
        v4f red = acc[t];
        red += shfl_xor4(red, 4);
        red += shfl_xor4(red, 8);
        red += shfl_xor4(red, 16);
        red += shfl_xor4(red, 32);
        if (slot == 0) {
            int j = jw + t;
            v4f mi = *(const v4f*)(inr + (size_t)j * CP + cq4);
            v4f res = cid * mi + red;
            *(v4f*)(outr + (size_t)j * CP + cq4) = res;
            rsum += res;
        }
    }
    if (slot == 0) *(v4f*)&npart[wave][cq4] = rsum;
    __syncthreads();
    if (tid < 16) {
        float s = npart[0][tid] + npart[1][tid] + npart[2][tid] + npart[3][tid];
        atomicAdd(&normv[r * 128 + p * CP + tid], s);
    }
}

// ---------------- epilogue ----------------
__global__ void rnorm_kernel(const float* __restrict__ normv, float* __restrict__ rnormv) {
    int i = threadIdx.x;
    rnormv[i] = 1.f / fmaxf(normv[i], 1e-20f);
}

__global__ void final_kernel(const float* __restrict__ mem3, const float* __restrict__ rnormv,
                             float* __restrict__ out) {
    __shared__ float tile[32 * 129];
    __shared__ float rn[384];
    for (int idx = threadIdx.x; idx < 384; idx += 256) rn[idx] = rnormv[idx];
    __syncthreads();
    int j0 = blockIdx.x * 32;
    for (int p = 0; p < NPASS; ++p) {
        for (int it = 0; it < 2; ++it) {
            int lin = it * 256 + threadIdx.x;
            int jj = lin >> 4, c = lin & 15;
            int b = p * CP + c;
            float s = 0.f;
            for (int r = 0; r < 3; ++r)
                s += mem3[((size_t)(r * NPASS + p) * NENT + j0 + jj) * CP + c] * rn[r * 128 + b];
            tile[jj * 129 + b] = s;
        }
    }
    __syncthreads();
    for (int it = 0; it < 16; ++it) {
        int lin = it * 256 + threadIdx.x;
        int b = lin >> 5, jj = lin & 31;
        out[(size_t)b * NENT + j0 + jj] = tile[jj * 129 + b];
    }
}

extern "C" void kernel_launch(void* const* d_in, const int* in_sizes, int n_in,
                              void* d_out, int out_size, void* d_ws, size_t ws_size,
                              hipStream_t stream) {
    const int*   queries  = (const int*)d_in[0];
    const int*   heads    = (const int*)d_in[1];
    const int*   edge_src = (const int*)d_in[2];
    const int*   edge_dst = (const int*)d_in[3];
    const float* edge_val = (const float*)d_in[4];
    const float* emb      = (const float*)d_in[5];
    const float* Wih_f    = (const float*)d_in[6];
    const float* Whh_f    = (const float*)d_in[7];
    const float* bih_f    = (const float*)d_in[8];
    const float* bhh_f    = (const float*)d_in[9];
    const float* Wih_b    = (const float*)d_in[10];
    const float* Whh_b    = (const float*)d_in[11];
    const float* bih_b    = (const float*)d_in[12];
    const float* bhh_b    = (const float*)d_in[13];
    const float* W0       = (const float*)d_in[14];
    const float* b0       = (const float*)d_in[15];
    float* out = (float*)d_out;

    char* w = (char*)d_ws;
    size_t off = 0;
    auto alloc = [&](size_t bytes) -> void* {
        off = (off + 255) & ~(size_t)255;
        void* p = w + off;
        off += bytes;
        return p;
    };
    float* attnq  = (float*)alloc((size_t)9 * 13 * NQ * sizeof(float));
    float* attn   = (float*)alloc((size_t)9 * 13 * 128 * sizeof(float));
    float* zxq    = (float*)alloc((size_t)6 * NQ * 512 * sizeof(float));
    float* hq     = (float*)alloc((size_t)6 * 3 * NQ * 128 * sizeof(float));
    // meta block (single memset): bmH | bm2 | fillD | fillS
    unsigned* bmH = (unsigned*)alloc((2 * 1250 + 2 * NENT) * sizeof(int));
    unsigned* bm2 = bmH + 1250;
    int* fillD    = (int*)(bm2 + 1250);
    int* fillS    = fillD + NENT;
    int2*  eD     = (int2*)alloc((size_t)NENT * ECAP * sizeof(int2));
    float* mem2   = (float*)alloc((size_t)NRANK * NENT * NB * sizeof(float));
    float* mem3   = (float*)alloc((size_t)NRANK * NENT * NB * sizeof(float));
    int2*  eS     = (int2*)mem3;   // alias: eS lifetime (build..fused01) ends before mem3's (dense..final)
    float* normv  = (float*)alloc((size_t)NRANK * NB * sizeof(float));
    float* rnormv = (float*)alloc((size_t)NRANK * NB * sizeof(float));

    int cooGrid = (NTOT + 255) / 256;

    // bitmaps + fills (one memset), then single-pass ELL build
    hipMemsetAsync(bmH, 0, (2 * 1250 + 2 * NENT) * sizeof(int), stream);
    headmark_kernel<<<1, 128, 0, stream>>>(heads, bmH, bm2);
    mark2_kernel<<<cooGrid, 256, 0, stream>>>(edge_src, edge_dst, bmH, bm2);
    build_ell_kernel<<<cooGrid, 256, 0, stream>>>(edge_src, edge_dst, edge_val, bm2,
                                                  fillD, fillS, eD, eS);

    // LSTM + attention (deduped over 24 queries)
    zxq_kernel<<<6 * NQ, 128, 0, stream>>>(emb, Wih_f, bih_f, bhh_f, Wih_b, bih_b, bhh_b, zxq);
    lstmq_kernel<<<6 * NQ, 128, 0, stream>>>(Whh_f, Whh_b, zxq, hq);
    attnq_kernel<<<9, 32, 0, stream>>>(hq, W0, b0, attnq);
    expand_kernel<<<1, 256, 0, stream>>>(queries, attnq, attn);

    // steps 0+1 sparse, step 2 dense (norm fused into dense)
    hipMemsetAsync(mem2, 0, (size_t)NRANK * NENT * NB * sizeof(float), stream);
    hipMemsetAsync(normv, 0, NRANK * NB * sizeof(float), stream);
    {
        dim3 g(NB, NRANK);
        fused01_kernel<<<g, 128, 0, stream>>>(heads, attn, fillS, eS, mem2);
    }
    {
        dim3 g(NPASS, NENT / 16, NRANK);
        dense_kernel<<<g, 256, 0, stream>>>(attn, fillD, eD, mem2, mem3, normv);
    }

    // epilogue
    rnorm_kernel<<<1, NRANK * NB, 0, stream>>>(normv, rnormv);
    final_kernel<<<NENT / 32, 256, 0, stream>>>(mem3, rnormv, out);
}